// Round 4
// baseline (1792.260 us; speedup 1.0000x reference)
//
#include <hip/hip_runtime.h>
#include <math.h>

#define D_MODEL 1024
#define D_INNER 2048
#define D_STATE 16
#define DT_RANK 64
#define LSEQ    2048
#define NTOK    4096   // B * L

typedef short bf16x8 __attribute__((ext_vector_type(8)));
typedef float f32x4  __attribute__((ext_vector_type(4)));

__device__ __forceinline__ unsigned bf16_rne(float v) {
    unsigned u = __float_as_uint(v);
    return (u + 0x7FFFu + ((u >> 16) & 1u)) >> 16;
}
__device__ __forceinline__ void split_hi_lo(float v, short& h, short& l) {
    unsigned hb = bf16_rne(v);
    h = (short)hb;
    float r = v - __uint_as_float(hb << 16);
    l = (short)bf16_rne(r);
}

// ---------------------------------------------------------------- LayerNorm -> bf16 hi/lo
__global__ __launch_bounds__(256) void ln_kernel(const float* __restrict__ x,
                                                 const float* __restrict__ w,
                                                 const float* __restrict__ b,
                                                 short* __restrict__ nh,
                                                 short* __restrict__ nl)
{
    int t = blockIdx.x;
    const float4* xr = (const float4*)(x + (size_t)t * D_MODEL);
    float4 v = xr[threadIdx.x];
    float s  = v.x + v.y + v.z + v.w;
    float s2 = v.x*v.x + v.y*v.y + v.z*v.z + v.w*v.w;
    for (int off = 32; off > 0; off >>= 1) {
        s  += __shfl_down(s, off);
        s2 += __shfl_down(s2, off);
    }
    __shared__ float red[8];
    int wid = threadIdx.x >> 6, lane = threadIdx.x & 63;
    if (lane == 0) { red[wid] = s; red[4 + wid] = s2; }
    __syncthreads();
    if (threadIdx.x == 0) {
        float a = red[0] + red[1] + red[2] + red[3];
        float c = red[4] + red[5] + red[6] + red[7];
        red[0] = a * (1.f / (float)D_MODEL);
        red[4] = c * (1.f / (float)D_MODEL);
    }
    __syncthreads();
    float mu  = red[0];
    float var = red[4] - mu * mu;
    float rs  = rsqrtf(var + 1e-5f);
    float4 wv = ((const float4*)w)[threadIdx.x];
    float4 bv = ((const float4*)b)[threadIdx.x];
    float4 o;
    o.x = (v.x - mu) * rs * wv.x + bv.x;
    o.y = (v.y - mu) * rs * wv.y + bv.y;
    o.z = (v.z - mu) * rs * wv.z + bv.z;
    o.w = (v.w - mu) * rs * wv.w + bv.w;
    short4 h4, l4;
    split_hi_lo(o.x, h4.x, l4.x);
    split_hi_lo(o.y, h4.y, l4.y);
    split_hi_lo(o.z, h4.z, l4.z);
    split_hi_lo(o.w, h4.w, l4.w);
    size_t off = (size_t)t * D_MODEL + threadIdx.x * 4;
    *(short4*)&nh[off] = h4;
    *(short4*)&nl[off] = l4;
}

// -------------------------------------------- transpose + split fp32 W[R][C] -> [C][R] bf16 hi/lo
__global__ __launch_bounds__(256) void cvtT_k(const float* __restrict__ W,
                                              short* __restrict__ Th,
                                              short* __restrict__ Tl,
                                              int R, int Cc)
{
    __shared__ float t[64][65];
    int rr = threadIdx.x >> 4;
    int cc = (threadIdx.x & 15) << 2;
    int r0 = blockIdx.y * 64, c0 = blockIdx.x * 64;
#pragma unroll
    for (int s = 0; s < 4; ++s) {
        float4 v = *(const float4*)&W[(size_t)(r0 + rr + 16*s) * Cc + c0 + cc];
        t[rr+16*s][cc+0] = v.x; t[rr+16*s][cc+1] = v.y;
        t[rr+16*s][cc+2] = v.z; t[rr+16*s][cc+3] = v.w;
    }
    __syncthreads();
#pragma unroll
    for (int s = 0; s < 4; ++s) {
        int orow = rr + 16*s;
        short4 h4, l4;
        split_hi_lo(t[cc+0][orow], h4.x, l4.x);
        split_hi_lo(t[cc+1][orow], h4.y, l4.y);
        split_hi_lo(t[cc+2][orow], h4.z, l4.z);
        split_hi_lo(t[cc+3][orow], h4.w, l4.w);
        size_t off = (size_t)(c0 + orow) * R + r0 + cc;
        *(short4*)&Th[off] = h4;
        *(short4*)&Tl[off] = l4;
    }
}

// ---------------------------------------------------------------- bf16x3 MFMA GEMM
// C[M,N] = A[M,K] @ B[N,K]^T  via  Ah·Bh + Al·Bh + Ah·Bl, fp32 accum.
// A,B pre-split bf16 row-major [rows][K]. M%128==0, N%128==0, K%32==0.
// EPI 0: store; EPI 2: + aux[row*ldc+col]
template<int EPI>
__global__ __launch_bounds__(256) void mgemm_k(const short* __restrict__ Ah,
                                               const short* __restrict__ Al,
                                               const short* __restrict__ Bh,
                                               const short* __restrict__ Bl,
                                               float* __restrict__ C, int ldc,
                                               int K, const float* __restrict__ aux)
{
    __shared__ short lds[4][128 * 32];   // Ah | Al | Bh | Bl tiles, [row][k] linear

    int tid  = threadIdx.x;
    int w    = tid >> 6;          // wave 0..3
    int lane = tid & 63;
    int wr   = w >> 1, wc = w & 1;
    int row0 = blockIdx.y * 128;
    int col0 = blockIdx.x * 128;

    // wave w stages buffer w: 0=Ah 1=Al 2=Bh 3=Bl
    const short* gA = (w & 1) ? Al : Ah;
    const short* gB = (w & 1) ? Bl : Bh;
    const short* g  = (w & 2) ? gB : gA;
    int obase       = (w & 2) ? col0 : row0;
    const short* gtile = g + (size_t)obase * K;

    int srow  = lane >> 2;         // 0..15 row within 16-row chunk
    int skoff = (lane & 3) * 8;    // 0,8,16,24 shorts

    int fr = lane & 15;            // fragment row/col
    int kg = lane >> 4;            // k-group 0..3

    f32x4 acc[4][4] = {};

    for (int k0 = 0; k0 < K; k0 += 32) {
        bf16x8 stg[8];
#pragma unroll
        for (int i = 0; i < 8; ++i)
            stg[i] = *(const bf16x8*)(gtile + (size_t)(i * 16 + srow) * K + k0 + skoff);
        __syncthreads();   // previous tile's readers done
#pragma unroll
        for (int i = 0; i < 8; ++i)
            *(bf16x8*)&lds[w][i * 512 + lane * 8] = stg[i];
        __syncthreads();   // tile visible

        bf16x8 a_h[4], a_l[4], b_h[4], b_l[4];
#pragma unroll
        for (int m = 0; m < 4; ++m) {
            int ra = (wr * 64 + m * 16 + fr) * 32 + kg * 8;
            int rb = (wc * 64 + m * 16 + fr) * 32 + kg * 8;
            a_h[m] = *(const bf16x8*)&lds[0][ra];
            a_l[m] = *(const bf16x8*)&lds[1][ra];
            b_h[m] = *(const bf16x8*)&lds[2][rb];
            b_l[m] = *(const bf16x8*)&lds[3][rb];
        }
#pragma unroll
        for (int m = 0; m < 4; ++m)
#pragma unroll
            for (int n = 0; n < 4; ++n)
                acc[m][n] = __builtin_amdgcn_mfma_f32_16x16x32_bf16(a_h[m], b_h[n], acc[m][n], 0, 0, 0);
#pragma unroll
        for (int m = 0; m < 4; ++m)
#pragma unroll
            for (int n = 0; n < 4; ++n)
                acc[m][n] = __builtin_amdgcn_mfma_f32_16x16x32_bf16(a_l[m], b_h[n], acc[m][n], 0, 0, 0);
#pragma unroll
        for (int m = 0; m < 4; ++m)
#pragma unroll
            for (int n = 0; n < 4; ++n)
                acc[m][n] = __builtin_amdgcn_mfma_f32_16x16x32_bf16(a_h[m], b_l[n], acc[m][n], 0, 0, 0);
    }

    // C/D layout (m89-verified): col = lane&15, row = (lane>>4)*4 + reg
#pragma unroll
    for (int m = 0; m < 4; ++m) {
        int row = row0 + wr * 64 + m * 16 + kg * 4;
#pragma unroll
        for (int n = 0; n < 4; ++n) {
            int col = col0 + wc * 64 + n * 16 + fr;
#pragma unroll
            for (int j = 0; j < 4; ++j) {
                size_t off = (size_t)(row + j) * ldc + col;
                float v = acc[m][n][j];
                if (EPI == 2) v += aux[off];
                C[off] = v;
            }
        }
    }
}

// ---------------------------------------------------------------- SGEMM 128x128 fp32 (dt-proj)
#define TBM 128
#define TBN 128
#define TBK 16

template<int EPI>
__global__ __launch_bounds__(256) void sgemm128_k(const float* __restrict__ A, int lda,
                                                  const float* __restrict__ B, int ldb,
                                                  float* __restrict__ C, int ldc,
                                                  int K, const float* __restrict__ aux)
{
    __shared__ float As[TBK][TBM + 4];
    __shared__ float Bs[TBK][TBN + 4];

    int tid  = threadIdx.x;
    int row0 = blockIdx.y * TBM;
    int col0 = blockIdx.x * TBN;

    int arow = tid >> 2;
    int acol = (tid & 3) << 2;
    int brow = tid >> 5;
    int bcol = (tid & 31) << 2;

    int tr = tid >> 4;
    int tc = tid & 15;

    float acc[8][8] = {};

    for (int k0 = 0; k0 < K; k0 += TBK) {
        float4 a0 = *(const float4*)(A + (size_t)(row0 + arow)      * lda + k0 + acol);
        float4 a1 = *(const float4*)(A + (size_t)(row0 + arow + 64) * lda + k0 + acol);
        float4 b0 = *(const float4*)(B + (size_t)(k0 + brow)     * ldb + col0 + bcol);
        float4 b1 = *(const float4*)(B + (size_t)(k0 + brow + 8) * ldb + col0 + bcol);
        __syncthreads();
        As[acol + 0][arow] = a0.x;
        As[acol + 1][arow] = a0.y;
        As[acol + 2][arow] = a0.z;
        As[acol + 3][arow] = a0.w;
        As[acol + 0][arow + 64] = a1.x;
        As[acol + 1][arow + 64] = a1.y;
        As[acol + 2][arow + 64] = a1.z;
        As[acol + 3][arow + 64] = a1.w;
        *(float4*)&Bs[brow][bcol]     = b0;
        *(float4*)&Bs[brow + 8][bcol] = b1;
        __syncthreads();
#pragma unroll
        for (int kk = 0; kk < TBK; ++kk) {
            float4 x0 = *(const float4*)&As[kk][tr << 2];
            float4 x1 = *(const float4*)&As[kk][(tr << 2) + 64];
            float4 y0 = *(const float4*)&Bs[kk][tc << 2];
            float4 y1 = *(const float4*)&Bs[kk][(tc << 2) + 64];
            float xa[8] = {x0.x, x0.y, x0.z, x0.w, x1.x, x1.y, x1.z, x1.w};
            float yb[8] = {y0.x, y0.y, y0.z, y0.w, y1.x, y1.y, y1.z, y1.w};
#pragma unroll
            for (int i = 0; i < 8; ++i)
#pragma unroll
                for (int j = 0; j < 8; ++j)
                    acc[i][j] = fmaf(xa[i], yb[j], acc[i][j]);
        }
    }

#pragma unroll
    for (int ih = 0; ih < 2; ++ih) {
#pragma unroll
        for (int i = 0; i < 4; ++i) {
            int r = row0 + (tr << 2) + ih * 64 + i;
#pragma unroll
            for (int jh = 0; jh < 2; ++jh) {
                int c = col0 + (tc << 2) + jh * 64;
                size_t off = (size_t)r * ldc + c;
                float4 v = *(const float4*)&acc[ih * 4 + i][jh * 4];
                if (EPI == 1) {
                    float4 bb = *(const float4*)(aux + c);
                    float t0;
                    t0 = v.x + bb.x; v.x = fmaxf(t0, 0.f) + log1pf(expf(-fabsf(t0)));
                    t0 = v.y + bb.y; v.y = fmaxf(t0, 0.f) + log1pf(expf(-fabsf(t0)));
                    t0 = v.z + bb.z; v.z = fmaxf(t0, 0.f) + log1pf(expf(-fabsf(t0)));
                    t0 = v.w + bb.w; v.w = fmaxf(t0, 0.f) + log1pf(expf(-fabsf(t0)));
                } else if (EPI == 2) {
                    float4 rr = *(const float4*)(aux + off);
                    v.x += rr.x; v.y += rr.y; v.z += rr.z; v.w += rr.w;
                }
                *(float4*)(C + off) = v;
            }
        }
    }
}

// ---------------------------------------------------------------- SGEMM 64x64 (ragged N, xproj)
#define GBM 64
#define GBN 64
#define GBK 16

__global__ __launch_bounds__(256) void sgemm64_k(const float* __restrict__ A, int lda,
                                                 const float* __restrict__ B, int ldb,
                                                 float* __restrict__ C, int ldc,
                                                 int N, int K)
{
    __shared__ float As[GBK][GBM + 4];
    __shared__ float Bs[GBK][GBN + 4];

    int tid  = threadIdx.x;
    int row0 = blockIdx.y * GBM;
    int col0 = blockIdx.x * GBN;

    int ar = tid >> 2;
    int ac = (tid & 3) << 2;
    int br = tid >> 4;
    int bc = (tid & 15) << 2;

    int tr = tid >> 4;
    int tc = tid & 15;

    float acc[4][4] = {};

    for (int k0 = 0; k0 < K; k0 += GBK) {
        float4 av = *(const float4*)(A + (size_t)(row0 + ar) * lda + k0 + ac);
        float4 bv;
        int gcol = col0 + bc;
        if (gcol + 3 < N) {
            bv = *(const float4*)(B + (size_t)(k0 + br) * ldb + gcol);
        } else {
            const float* brow_p = B + (size_t)(k0 + br) * ldb;
            bv.x = (gcol + 0 < N) ? brow_p[gcol + 0] : 0.f;
            bv.y = (gcol + 1 < N) ? brow_p[gcol + 1] : 0.f;
            bv.z = (gcol + 2 < N) ? brow_p[gcol + 2] : 0.f;
            bv.w = (gcol + 3 < N) ? brow_p[gcol + 3] : 0.f;
        }
        __syncthreads();
        As[ac + 0][ar] = av.x;
        As[ac + 1][ar] = av.y;
        As[ac + 2][ar] = av.z;
        As[ac + 3][ar] = av.w;
        *(float4*)&Bs[br][bc] = bv;
        __syncthreads();
#pragma unroll
        for (int kk = 0; kk < GBK; ++kk) {
            float4 a = *(const float4*)&As[kk][tr << 2];
            float4 b = *(const float4*)&Bs[kk][tc << 2];
            acc[0][0] += a.x * b.x; acc[0][1] += a.x * b.y; acc[0][2] += a.x * b.z; acc[0][3] += a.x * b.w;
            acc[1][0] += a.y * b.x; acc[1][1] += a.y * b.y; acc[1][2] += a.y * b.z; acc[1][3] += a.y * b.w;
            acc[2][0] += a.z * b.x; acc[2][1] += a.z * b.y; acc[2][2] += a.z * b.z; acc[2][3] += a.z * b.w;
            acc[3][0] += a.w * b.x; acc[3][1] += a.w * b.y; acc[3][2] += a.w * b.z; acc[3][3] += a.w * b.w;
        }
    }

    int r0 = row0 + (tr << 2);
    int c0 = col0 + (tc << 2);
#pragma unroll
    for (int i = 0; i < 4; ++i) {
#pragma unroll
        for (int j = 0; j < 4; ++j) {
            int c = c0 + j;
            if (c < N) C[(size_t)(r0 + i) * ldc + c] = acc[i][j];
        }
    }
}

// ------------------------------------------------- depthwise causal conv + SiLU
__global__ __launch_bounds__(256) void conv_silu_kernel(const float* __restrict__ xz,
                                                        const float* __restrict__ conv_w,
                                                        const float* __restrict__ conv_b,
                                                        float* __restrict__ uc)
{
    int idx = blockIdx.x * 256 + threadIdx.x;
    if (idx >= NTOK * D_INNER) return;
    int d  = idx & (D_INNER - 1);
    int bl = idx >> 11;
    int l  = bl & (LSEQ - 1);
    float4 w = ((const float4*)conv_w)[d];
    float acc = conv_b[d];
    if (l >= 3) acc += w.x * xz[(size_t)(bl - 3) * (2 * D_INNER) + d];
    if (l >= 2) acc += w.y * xz[(size_t)(bl - 2) * (2 * D_INNER) + d];
    if (l >= 1) acc += w.z * xz[(size_t)(bl - 1) * (2 * D_INNER) + d];
    acc += w.w * xz[(size_t)bl * (2 * D_INNER) + d];
    uc[idx] = acc / (1.f + expf(-acc));
}

// ---------------------------------------------------------------- selective scan
__global__ __launch_bounds__(256) void scan_kernel(const float* __restrict__ delta,
                                                   const float* __restrict__ uc,
                                                   const float* __restrict__ dbc,
                                                   const float* __restrict__ xz,
                                                   const float* __restrict__ A_log,
                                                   const float* __restrict__ Dp,
                                                   short* __restrict__ ygh,
                                                   short* __restrict__ ygl)
{
    int tid = threadIdx.x;
    int g = tid >> 4, n = tid & 15;
    int bid = blockIdx.x;
    int b = bid >> 7;
    int d = (bid & 127) * 16 + g;
    float Adn = -expf(A_log[d * D_STATE + n]);
    float Dv  = Dp[d];
    float h = 0.f;
    size_t rowb = (size_t)b * LSEQ;

    float dv = delta[rowb * D_INNER + d];
    float uv = uc[rowb * D_INNER + d];
    float Bv = dbc[rowb * 96 + DT_RANK + n];
    float Cv = dbc[rowb * 96 + DT_RANK + D_STATE + n];

    for (int l = 0; l < LSEQ; ++l) {
        float dv_n = 0.f, uv_n = 0.f, Bv_n = 0.f, Cv_n = 0.f;
        if (l + 1 < LSEQ) {
            size_t r = rowb + l + 1;
            dv_n = delta[r * D_INNER + d];
            uv_n = uc[r * D_INNER + d];
            Bv_n = dbc[r * 96 + DT_RANK + n];
            Cv_n = dbc[r * 96 + DT_RANK + D_STATE + n];
        }
        float dA = expf(dv * Adn);
        h = fmaf(dA, h, dv * uv * Bv);
        float p = h * Cv;
        p += __shfl_xor(p, 1);
        p += __shfl_xor(p, 2);
        p += __shfl_xor(p, 4);
        p += __shfl_xor(p, 8);
        if (n == 0) {
            size_t r = rowb + l;
            float zv = xz[r * (2 * D_INNER) + D_INNER + d];
            float y  = fmaf(uv, Dv, p);
            float val = y * (zv / (1.f + expf(-zv)));
            short hh, ll;
            split_hi_lo(val, hh, ll);
            ygh[r * D_INNER + d] = hh;
            ygl[r * D_INNER + d] = ll;
        }
        dv = dv_n; uv = uv_n; Bv = Bv_n; Cv = Cv_n;
    }
}

// ---------------------------------------------------------------- launch
extern "C" void kernel_launch(void* const* d_in, const int* in_sizes, int n_in,
                              void* d_out, int out_size, void* d_ws, size_t ws_size,
                              hipStream_t stream)
{
    const float* x      = (const float*)d_in[0];
    const float* ln_w   = (const float*)d_in[1];
    const float* ln_b   = (const float*)d_in[2];
    const float* W_in   = (const float*)d_in[3];
    const float* conv_w = (const float*)d_in[4];
    const float* conv_b = (const float*)d_in[5];
    const float* W_xprj = (const float*)d_in[6];
    const float* W_dt   = (const float*)d_in[7];
    const float* b_dt   = (const float*)d_in[8];
    const float* A_log  = (const float*)d_in[9];
    const float* Dp     = (const float*)d_in[10];
    const float* W_out  = (const float*)d_in[11];
    float* out = (float*)d_out;

    // fp32 segments: 135,790,592 B
    float* xz    = (float*)d_ws;                          // 4096*4096
    float* uc    = xz    + (size_t)NTOK * 2 * D_INNER;    // 4096*2048
    float* dbc   = uc    + (size_t)NTOK * D_INNER;        // 4096*96
    float* delta = dbc   + (size_t)NTOK * 96;             // 4096*2048
    // bf16 (short) region: 20 Mi shorts = 41,943,040 B, phase-reused
    short* s0    = (short*)(delta + (size_t)NTOK * D_INNER);
    // phase A (LN -> GEMM1): [0,16M) shorts
    short* nh    = s0;
    short* nl    = nh   + (size_t)NTOK * D_MODEL;
    short* wiTh  = nl   + (size_t)NTOK * D_MODEL;
    short* wiTl  = wiTh + (size_t)(2 * D_INNER) * D_MODEL;
    // phase B (scan -> GEMM-out): ygh/ygl alias [0,16M); woT at [16M,20M) (no overlap with A)
    short* ygh   = s0;
    short* ygl   = ygh  + (size_t)NTOK * D_INNER;
    short* woTh  = ygl  + (size_t)NTOK * D_INNER;
    short* woTl  = woTh + (size_t)D_MODEL * D_INNER;

    size_t needed = (size_t)135790592 + (size_t)41943040;
    if (ws_size < needed) return;   // clean mismatch signal instead of OOB fault

    // 0. weight transpose+split
    cvtT_k<<<dim3(2 * D_INNER / 64, D_MODEL / 64), 256, 0, stream>>>(W_in, wiTh, wiTl, D_MODEL, 2 * D_INNER);
    cvtT_k<<<dim3(D_MODEL / 64, D_INNER / 64), 256, 0, stream>>>(W_out, woTh, woTl, D_INNER, D_MODEL);
    // 1. LayerNorm -> bf16 hi/lo
    ln_kernel<<<NTOK, 256, 0, stream>>>(x, ln_w, ln_b, nh, nl);
    // 2. xz = normed @ W_in   (bf16x3 MFMA)  [4096,1024]@[1024,4096]
    mgemm_k<0><<<dim3(2 * D_INNER / 128, NTOK / 128), 256, 0, stream>>>(
        nh, nl, wiTh, wiTl, xz, 2 * D_INNER, D_MODEL, nullptr);
    // 3. depthwise conv + SiLU
    conv_silu_kernel<<<(NTOK * D_INNER) / 256, 256, 0, stream>>>(xz, conv_w, conv_b, uc);
    // 4. dbc = uc @ W_xproj   [4096,2048]@[2048,96]
    sgemm64_k<<<dim3(2, NTOK / GBM), 256, 0, stream>>>(
        uc, D_INNER, W_xprj, 96, dbc, 96, 96, D_INNER);
    // 5. delta = softplus(dt @ W_dt + b_dt)   [4096,64]@[64,2048]
    sgemm128_k<1><<<dim3(D_INNER / TBN, NTOK / TBM), 256, 0, stream>>>(
        dbc, 96, W_dt, D_INNER, delta, D_INNER, DT_RANK, b_dt);
    // 6. selective scan + gating -> bf16 hi/lo (writes alias dead phase-A buffers)
    scan_kernel<<<256, 256, 0, stream>>>(delta, uc, dbc, xz, A_log, Dp, ygh, ygl);
    // 7. out = x + yg @ W_out  (bf16x3 MFMA)  [4096,2048]@[2048,1024]
    mgemm_k<2><<<dim3(D_MODEL / 128, NTOK / 128), 256, 0, stream>>>(
        ygh, ygl, woTh, woTl, out, D_MODEL, D_INNER, x);
}

// Round 6
// 848.577 us; speedup vs baseline: 2.1121x; 2.1121x over previous
//
#include <hip/hip_runtime.h>
#include <math.h>

#define D_MODEL 1024
#define D_INNER 2048
#define D_STATE 16
#define DT_RANK 64
#define LSEQ    2048
#define NTOK    4096   // B * L
#define SCH     32     // scan chunks
#define SCL     (LSEQ / SCH)   // 64 steps per chunk

typedef short bf16x8 __attribute__((ext_vector_type(8)));
typedef float f32x4  __attribute__((ext_vector_type(4)));

__device__ __forceinline__ unsigned bf16_rne(float v) {
    unsigned u = __float_as_uint(v);
    return (u + 0x7FFFu + ((u >> 16) & 1u)) >> 16;
}
__device__ __forceinline__ void split_hi_lo(float v, short& h, short& l) {
    unsigned hb = bf16_rne(v);
    h = (short)hb;
    float r = v - __uint_as_float(hb << 16);
    l = (short)bf16_rne(r);
}

// ---------------------------------------------------------------- LayerNorm -> bf16 hi/lo
__global__ __launch_bounds__(256) void ln_kernel(const float* __restrict__ x,
                                                 const float* __restrict__ w,
                                                 const float* __restrict__ b,
                                                 short* __restrict__ nh,
                                                 short* __restrict__ nl)
{
    int t = blockIdx.x;
    const float4* xr = (const float4*)(x + (size_t)t * D_MODEL);
    float4 v = xr[threadIdx.x];
    float s  = v.x + v.y + v.z + v.w;
    float s2 = v.x*v.x + v.y*v.y + v.z*v.z + v.w*v.w;
    for (int off = 32; off > 0; off >>= 1) {
        s  += __shfl_down(s, off);
        s2 += __shfl_down(s2, off);
    }
    __shared__ float red[8];
    int wid = threadIdx.x >> 6, lane = threadIdx.x & 63;
    if (lane == 0) { red[wid] = s; red[4 + wid] = s2; }
    __syncthreads();
    if (threadIdx.x == 0) {
        float a = red[0] + red[1] + red[2] + red[3];
        float c = red[4] + red[5] + red[6] + red[7];
        red[0] = a * (1.f / (float)D_MODEL);
        red[4] = c * (1.f / (float)D_MODEL);
    }
    __syncthreads();
    float mu  = red[0];
    float var = red[4] - mu * mu;
    float rs  = rsqrtf(var + 1e-5f);
    float4 wv = ((const float4*)w)[threadIdx.x];
    float4 bv = ((const float4*)b)[threadIdx.x];
    float4 o;
    o.x = (v.x - mu) * rs * wv.x + bv.x;
    o.y = (v.y - mu) * rs * wv.y + bv.y;
    o.z = (v.z - mu) * rs * wv.z + bv.z;
    o.w = (v.w - mu) * rs * wv.w + bv.w;
    short4 h4, l4;
    split_hi_lo(o.x, h4.x, l4.x);
    split_hi_lo(o.y, h4.y, l4.y);
    split_hi_lo(o.z, h4.z, l4.z);
    split_hi_lo(o.w, h4.w, l4.w);
    size_t off = (size_t)t * D_MODEL + threadIdx.x * 4;
    *(short4*)&nh[off] = h4;
    *(short4*)&nl[off] = l4;
}

// -------------------------------------------- transpose + split fp32 W[R][C] -> [C][R] bf16 hi/lo
__global__ __launch_bounds__(256) void cvtT_k(const float* __restrict__ W,
                                              short* __restrict__ Th,
                                              short* __restrict__ Tl,
                                              int R, int Cc)
{
    __shared__ float t[64][65];
    int rr = threadIdx.x >> 4;
    int cc = (threadIdx.x & 15) << 2;
    int r0 = blockIdx.y * 64, c0 = blockIdx.x * 64;
#pragma unroll
    for (int s = 0; s < 4; ++s) {
        float4 v = *(const float4*)&W[(size_t)(r0 + rr + 16*s) * Cc + c0 + cc];
        t[rr+16*s][cc+0] = v.x; t[rr+16*s][cc+1] = v.y;
        t[rr+16*s][cc+2] = v.z; t[rr+16*s][cc+3] = v.w;
    }
    __syncthreads();
#pragma unroll
    for (int s = 0; s < 4; ++s) {
        int orow = rr + 16*s;
        short4 h4, l4;
        split_hi_lo(t[cc+0][orow], h4.x, l4.x);
        split_hi_lo(t[cc+1][orow], h4.y, l4.y);
        split_hi_lo(t[cc+2][orow], h4.z, l4.z);
        split_hi_lo(t[cc+3][orow], h4.w, l4.w);
        size_t off = (size_t)(c0 + orow) * R + r0 + cc;
        *(short4*)&Th[off] = h4;
        *(short4*)&Tl[off] = l4;
    }
}

// ---------------------------------------------------------------- bf16x3 MFMA GEMM
// C[M,N] = A[M,K] @ B[N,K]^T  via  Ah·Bh + Al·Bh + Ah·Bl, fp32 accum.
// LDS tile layout is fragment-major: [(rowgrp*4 + kchunk)][fr 0..15][8 shorts]
// so both staging writes and fragment reads are contiguous 1 KiB per wave
// (bank-conflict-free; old row-major layout was an 8-way conflict on reads).
template<int EPI>
__global__ __launch_bounds__(256) void mgemm_k(const short* __restrict__ Ah,
                                               const short* __restrict__ Al,
                                               const short* __restrict__ Bh,
                                               const short* __restrict__ Bl,
                                               float* __restrict__ C, int ldc,
                                               int K, const float* __restrict__ aux)
{
    __shared__ short lds[4][128 * 32];   // Ah | Al | Bh | Bl tiles

    int tid  = threadIdx.x;
    int w    = tid >> 6;
    int lane = tid & 63;
    int wr   = w >> 1, wc = w & 1;
    int row0 = blockIdx.y * 128;
    int col0 = blockIdx.x * 128;

    const short* gA = (w & 1) ? Al : Ah;
    const short* gB = (w & 1) ? Bl : Bh;
    const short* g  = (w & 2) ? gB : gA;
    int obase       = (w & 2) ? col0 : row0;
    const short* gtile = g + (size_t)obase * K;

    int srow  = lane >> 2;         // 0..15: row within 16-row group
    int skc   = lane & 3;          // 0..3 : k-chunk (8 shorts)
    int swoff = skc * 128 + srow * 8;   // shorts; += i*512 per 16-row group

    int fr = lane & 15;            // fragment row/col
    int kg = lane >> 4;            // k-chunk 0..3

    f32x4 acc[4][4] = {};

    for (int k0 = 0; k0 < K; k0 += 32) {
        bf16x8 stg[8];
#pragma unroll
        for (int i = 0; i < 8; ++i)
            stg[i] = *(const bf16x8*)(gtile + (size_t)(i * 16 + srow) * K + k0 + skc * 8);
        __syncthreads();   // previous tile's readers done
#pragma unroll
        for (int i = 0; i < 8; ++i)
            *(bf16x8*)&lds[w][i * 512 + swoff] = stg[i];
        __syncthreads();   // tile visible

        bf16x8 a_h[4], a_l[4], b_h[4], b_l[4];
#pragma unroll
        for (int m = 0; m < 4; ++m) {
            int ra = ((wr * 4 + m) * 4 + kg) * 128 + fr * 8;
            int rb = ((wc * 4 + m) * 4 + kg) * 128 + fr * 8;
            a_h[m] = *(const bf16x8*)&lds[0][ra];
            a_l[m] = *(const bf16x8*)&lds[1][ra];
            b_h[m] = *(const bf16x8*)&lds[2][rb];
            b_l[m] = *(const bf16x8*)&lds[3][rb];
        }
#pragma unroll
        for (int m = 0; m < 4; ++m)
#pragma unroll
            for (int n = 0; n < 4; ++n)
                acc[m][n] = __builtin_amdgcn_mfma_f32_16x16x32_bf16(a_h[m], b_h[n], acc[m][n], 0, 0, 0);
#pragma unroll
        for (int m = 0; m < 4; ++m)
#pragma unroll
            for (int n = 0; n < 4; ++n)
                acc[m][n] = __builtin_amdgcn_mfma_f32_16x16x32_bf16(a_l[m], b_h[n], acc[m][n], 0, 0, 0);
#pragma unroll
        for (int m = 0; m < 4; ++m)
#pragma unroll
            for (int n = 0; n < 4; ++n)
                acc[m][n] = __builtin_amdgcn_mfma_f32_16x16x32_bf16(a_h[m], b_l[n], acc[m][n], 0, 0, 0);
    }

    // C/D layout (m89-verified): col = lane&15, row = (lane>>4)*4 + reg
#pragma unroll
    for (int m = 0; m < 4; ++m) {
        int row = row0 + wr * 64 + m * 16 + kg * 4;
#pragma unroll
        for (int n = 0; n < 4; ++n) {
            int col = col0 + wc * 64 + n * 16 + fr;
#pragma unroll
            for (int j = 0; j < 4; ++j) {
                size_t off = (size_t)(row + j) * ldc + col;
                float v = acc[m][n][j];
                if (EPI == 2) v += aux[off];
                C[off] = v;
            }
        }
    }
}

// ---------------------------------------------------------------- SGEMM 128x128 fp32 (dt-proj)
#define TBM 128
#define TBN 128
#define TBK 16

template<int EPI>
__global__ __launch_bounds__(256) void sgemm128_k(const float* __restrict__ A, int lda,
                                                  const float* __restrict__ B, int ldb,
                                                  float* __restrict__ C, int ldc,
                                                  int K, const float* __restrict__ aux)
{
    __shared__ float As[TBK][TBM + 4];
    __shared__ float Bs[TBK][TBN + 4];

    int tid  = threadIdx.x;
    int row0 = blockIdx.y * TBM;
    int col0 = blockIdx.x * TBN;

    int arow = tid >> 2;
    int acol = (tid & 3) << 2;
    int brow = tid >> 5;
    int bcol = (tid & 31) << 2;

    int tr = tid >> 4;
    int tc = tid & 15;

    float acc[8][8] = {};

    for (int k0 = 0; k0 < K; k0 += TBK) {
        float4 a0 = *(const float4*)(A + (size_t)(row0 + arow)      * lda + k0 + acol);
        float4 a1 = *(const float4*)(A + (size_t)(row0 + arow + 64) * lda + k0 + acol);
        float4 b0 = *(const float4*)(B + (size_t)(k0 + brow)     * ldb + col0 + bcol);
        float4 b1 = *(const float4*)(B + (size_t)(k0 + brow + 8) * ldb + col0 + bcol);
        __syncthreads();
        As[acol + 0][arow] = a0.x;
        As[acol + 1][arow] = a0.y;
        As[acol + 2][arow] = a0.z;
        As[acol + 3][arow] = a0.w;
        As[acol + 0][arow + 64] = a1.x;
        As[acol + 1][arow + 64] = a1.y;
        As[acol + 2][arow + 64] = a1.z;
        As[acol + 3][arow + 64] = a1.w;
        *(float4*)&Bs[brow][bcol]     = b0;
        *(float4*)&Bs[brow + 8][bcol] = b1;
        __syncthreads();
#pragma unroll
        for (int kk = 0; kk < TBK; ++kk) {
            float4 x0 = *(const float4*)&As[kk][tr << 2];
            float4 x1 = *(const float4*)&As[kk][(tr << 2) + 64];
            float4 y0 = *(const float4*)&Bs[kk][tc << 2];
            float4 y1 = *(const float4*)&Bs[kk][(tc << 2) + 64];
            float xa[8] = {x0.x, x0.y, x0.z, x0.w, x1.x, x1.y, x1.z, x1.w};
            float yb[8] = {y0.x, y0.y, y0.z, y0.w, y1.x, y1.y, y1.z, y1.w};
#pragma unroll
            for (int i = 0; i < 8; ++i)
#pragma unroll
                for (int j = 0; j < 8; ++j)
                    acc[i][j] = fmaf(xa[i], yb[j], acc[i][j]);
        }
    }

#pragma unroll
    for (int ih = 0; ih < 2; ++ih) {
#pragma unroll
        for (int i = 0; i < 4; ++i) {
            int r = row0 + (tr << 2) + ih * 64 + i;
#pragma unroll
            for (int jh = 0; jh < 2; ++jh) {
                int c = col0 + (tc << 2) + jh * 64;
                size_t off = (size_t)r * ldc + c;
                float4 v = *(const float4*)&acc[ih * 4 + i][jh * 4];
                if (EPI == 1) {
                    float4 bb = *(const float4*)(aux + c);
                    float t0;
                    t0 = v.x + bb.x; v.x = fmaxf(t0, 0.f) + log1pf(expf(-fabsf(t0)));
                    t0 = v.y + bb.y; v.y = fmaxf(t0, 0.f) + log1pf(expf(-fabsf(t0)));
                    t0 = v.z + bb.z; v.z = fmaxf(t0, 0.f) + log1pf(expf(-fabsf(t0)));
                    t0 = v.w + bb.w; v.w = fmaxf(t0, 0.f) + log1pf(expf(-fabsf(t0)));
                } else if (EPI == 2) {
                    float4 rr = *(const float4*)(aux + off);
                    v.x += rr.x; v.y += rr.y; v.z += rr.z; v.w += rr.w;
                }
                *(float4*)(C + off) = v;
            }
        }
    }
}

// ---------------------------------------------------------------- SGEMM 64x64 (ragged N, xproj)
#define GBM 64
#define GBN 64
#define GBK 16

__global__ __launch_bounds__(256) void sgemm64_k(const float* __restrict__ A, int lda,
                                                 const float* __restrict__ B, int ldb,
                                                 float* __restrict__ C, int ldc,
                                                 int N, int K)
{
    __shared__ float As[GBK][GBM + 4];
    __shared__ float Bs[GBK][GBN + 4];

    int tid  = threadIdx.x;
    int row0 = blockIdx.y * GBM;
    int col0 = blockIdx.x * GBN;

    int ar = tid >> 2;
    int ac = (tid & 3) << 2;
    int br = tid >> 4;
    int bc = (tid & 15) << 2;

    int tr = tid >> 4;
    int tc = tid & 15;

    float acc[4][4] = {};

    for (int k0 = 0; k0 < K; k0 += GBK) {
        float4 av = *(const float4*)(A + (size_t)(row0 + ar) * lda + k0 + ac);
        float4 bv;
        int gcol = col0 + bc;
        if (gcol + 3 < N) {
            bv = *(const float4*)(B + (size_t)(k0 + br) * ldb + gcol);
        } else {
            const float* brow_p = B + (size_t)(k0 + br) * ldb;
            bv.x = (gcol + 0 < N) ? brow_p[gcol + 0] : 0.f;
            bv.y = (gcol + 1 < N) ? brow_p[gcol + 1] : 0.f;
            bv.z = (gcol + 2 < N) ? brow_p[gcol + 2] : 0.f;
            bv.w = (gcol + 3 < N) ? brow_p[gcol + 3] : 0.f;
        }
        __syncthreads();
        As[ac + 0][ar] = av.x;
        As[ac + 1][ar] = av.y;
        As[ac + 2][ar] = av.z;
        As[ac + 3][ar] = av.w;
        *(float4*)&Bs[br][bc] = bv;
        __syncthreads();
#pragma unroll
        for (int kk = 0; kk < GBK; ++kk) {
            float4 a = *(const float4*)&As[kk][tr << 2];
            float4 b = *(const float4*)&Bs[kk][tc << 2];
            acc[0][0] += a.x * b.x; acc[0][1] += a.x * b.y; acc[0][2] += a.x * b.z; acc[0][3] += a.x * b.w;
            acc[1][0] += a.y * b.x; acc[1][1] += a.y * b.y; acc[1][2] += a.y * b.z; acc[1][3] += a.y * b.w;
            acc[2][0] += a.z * b.x; acc[2][1] += a.z * b.y; acc[2][2] += a.z * b.z; acc[2][3] += a.z * b.w;
            acc[3][0] += a.w * b.x; acc[3][1] += a.w * b.y; acc[3][2] += a.w * b.z; acc[3][3] += a.w * b.w;
        }
    }

    int r0 = row0 + (tr << 2);
    int c0 = col0 + (tc << 2);
#pragma unroll
    for (int i = 0; i < 4; ++i) {
#pragma unroll
        for (int j = 0; j < 4; ++j) {
            int c = c0 + j;
            if (c < N) C[(size_t)(r0 + i) * ldc + c] = acc[i][j];
        }
    }
}

// ------------------------------------------------- depthwise causal conv + SiLU
__global__ __launch_bounds__(256) void conv_silu_kernel(const float* __restrict__ xz,
                                                        const float* __restrict__ conv_w,
                                                        const float* __restrict__ conv_b,
                                                        float* __restrict__ uc)
{
    int idx = blockIdx.x * 256 + threadIdx.x;
    if (idx >= NTOK * D_INNER) return;
    int d  = idx & (D_INNER - 1);
    int bl = idx >> 11;
    int l  = bl & (LSEQ - 1);
    float4 w = ((const float4*)conv_w)[d];
    float acc = conv_b[d];
    if (l >= 3) acc += w.x * xz[(size_t)(bl - 3) * (2 * D_INNER) + d];
    if (l >= 2) acc += w.y * xz[(size_t)(bl - 2) * (2 * D_INNER) + d];
    if (l >= 1) acc += w.z * xz[(size_t)(bl - 1) * (2 * D_INNER) + d];
    acc += w.w * xz[(size_t)bl * (2 * D_INNER) + d];
    uc[idx] = acc / (1.f + expf(-acc));
}

// ---------------------------------------------------------------- chunked scan
// pass 1: per (b,d,n,chunk) local scan from h=0 -> store (prod dA, h_end)
__global__ __launch_bounds__(256) void scan1_kernel(const float* __restrict__ delta,
                                                    const float* __restrict__ uc,
                                                    const float* __restrict__ dbc,
                                                    const float* __restrict__ A_log,
                                                    float* __restrict__ carry_A,
                                                    float* __restrict__ carry_h)
{
    int g = threadIdx.x >> 4, n = threadIdx.x & 15;
    int chunk = blockIdx.x;            // 0..31
    int d = blockIdx.y * 16 + g;       // 0..2047
    int b = blockIdx.z;                // 0..1
    float Adn = -expf(A_log[d * D_STATE + n]);
    float h = 0.f, Ap = 1.f;
    size_t r0 = (size_t)b * LSEQ + chunk * SCL;
#pragma unroll 4
    for (int l = 0; l < SCL; ++l) {
        size_t r = r0 + l;
        float dv = delta[r * D_INNER + d];
        float uv = uc[r * D_INNER + d];
        float Bv = dbc[r * 96 + DT_RANK + n];
        float dA = expf(dv * Adn);
        Ap *= dA;
        h = fmaf(dA, h, dv * uv * Bv);
    }
    size_t cbase = (((size_t)(b * D_INNER + d)) * D_STATE + n) * SCH + chunk;
    carry_A[cbase] = Ap;
    carry_h[cbase] = h;
}

// pass 2: sequential combine over chunks; overwrite carry_h with h_START per chunk
__global__ __launch_bounds__(256) void scan2_kernel(const float* __restrict__ carry_A,
                                                    float* __restrict__ carry_h)
{
    int idx = blockIdx.x * 256 + threadIdx.x;       // 0..65535 = (b*D_INNER+d)*16+n
    size_t base = (size_t)idx * SCH;
    float h = 0.f;
#pragma unroll
    for (int c = 0; c < SCH; ++c) {
        float Ap = carry_A[base + c];
        float he = carry_h[base + c];
        carry_h[base + c] = h;
        h = fmaf(Ap, h, he);
    }
}

// pass 3: re-scan with correct h_start, emit gated y (bf16 hi/lo)
__global__ __launch_bounds__(256) void scan3_kernel(const float* __restrict__ delta,
                                                    const float* __restrict__ uc,
                                                    const float* __restrict__ dbc,
                                                    const float* __restrict__ xz,
                                                    const float* __restrict__ A_log,
                                                    const float* __restrict__ Dp,
                                                    const float* __restrict__ carry_h,
                                                    short* __restrict__ ygh,
                                                    short* __restrict__ ygl)
{
    int g = threadIdx.x >> 4, n = threadIdx.x & 15;
    int chunk = blockIdx.x;
    int d = blockIdx.y * 16 + g;
    int b = blockIdx.z;
    float Adn = -expf(A_log[d * D_STATE + n]);
    float Dv  = Dp[d];
    size_t cbase = (((size_t)(b * D_INNER + d)) * D_STATE + n) * SCH + chunk;
    float h = carry_h[cbase];
    size_t r0 = (size_t)b * LSEQ + chunk * SCL;
    for (int l = 0; l < SCL; ++l) {
        size_t r = r0 + l;
        float dv = delta[r * D_INNER + d];
        float uv = uc[r * D_INNER + d];
        float Bv = dbc[r * 96 + DT_RANK + n];
        float Cv = dbc[r * 96 + DT_RANK + D_STATE + n];
        float dA = expf(dv * Adn);
        h = fmaf(dA, h, dv * uv * Bv);
        float p = h * Cv;
        p += __shfl_xor(p, 1);
        p += __shfl_xor(p, 2);
        p += __shfl_xor(p, 4);
        p += __shfl_xor(p, 8);
        if (n == 0) {
            float zv = xz[r * (2 * D_INNER) + D_INNER + d];
            float y  = fmaf(uv, Dv, p);
            float val = y * (zv / (1.f + expf(-zv)));
            short hh, ll;
            split_hi_lo(val, hh, ll);
            ygh[r * D_INNER + d] = hh;
            ygl[r * D_INNER + d] = ll;
        }
    }
}

// ---------------------------------------------------------------- serial scan (ws fallback)
__global__ __launch_bounds__(256) void scan_kernel(const float* __restrict__ delta,
                                                   const float* __restrict__ uc,
                                                   const float* __restrict__ dbc,
                                                   const float* __restrict__ xz,
                                                   const float* __restrict__ A_log,
                                                   const float* __restrict__ Dp,
                                                   short* __restrict__ ygh,
                                                   short* __restrict__ ygl)
{
    int tid = threadIdx.x;
    int g = tid >> 4, n = tid & 15;
    int bid = blockIdx.x;
    int b = bid >> 7;
    int d = (bid & 127) * 16 + g;
    float Adn = -expf(A_log[d * D_STATE + n]);
    float Dv  = Dp[d];
    float h = 0.f;
    size_t rowb = (size_t)b * LSEQ;

    float dv = delta[rowb * D_INNER + d];
    float uv = uc[rowb * D_INNER + d];
    float Bv = dbc[rowb * 96 + DT_RANK + n];
    float Cv = dbc[rowb * 96 + DT_RANK + D_STATE + n];

    for (int l = 0; l < LSEQ; ++l) {
        float dv_n = 0.f, uv_n = 0.f, Bv_n = 0.f, Cv_n = 0.f;
        if (l + 1 < LSEQ) {
            size_t r = rowb + l + 1;
            dv_n = delta[r * D_INNER + d];
            uv_n = uc[r * D_INNER + d];
            Bv_n = dbc[r * 96 + DT_RANK + n];
            Cv_n = dbc[r * 96 + DT_RANK + D_STATE + n];
        }
        float dA = expf(dv * Adn);
        h = fmaf(dA, h, dv * uv * Bv);
        float p = h * Cv;
        p += __shfl_xor(p, 1);
        p += __shfl_xor(p, 2);
        p += __shfl_xor(p, 4);
        p += __shfl_xor(p, 8);
        if (n == 0) {
            size_t r = rowb + l;
            float zv = xz[r * (2 * D_INNER) + D_INNER + d];
            float y  = fmaf(uv, Dv, p);
            float val = y * (zv / (1.f + expf(-zv)));
            short hh, ll;
            split_hi_lo(val, hh, ll);
            ygh[r * D_INNER + d] = hh;
            ygl[r * D_INNER + d] = ll;
        }
        dv = dv_n; uv = uv_n; Bv = Bv_n; Cv = Cv_n;
    }
}

// ---------------------------------------------------------------- launch
extern "C" void kernel_launch(void* const* d_in, const int* in_sizes, int n_in,
                              void* d_out, int out_size, void* d_ws, size_t ws_size,
                              hipStream_t stream)
{
    const float* x      = (const float*)d_in[0];
    const float* ln_w   = (const float*)d_in[1];
    const float* ln_b   = (const float*)d_in[2];
    const float* W_in   = (const float*)d_in[3];
    const float* conv_w = (const float*)d_in[4];
    const float* conv_b = (const float*)d_in[5];
    const float* W_xprj = (const float*)d_in[6];
    const float* W_dt   = (const float*)d_in[7];
    const float* b_dt   = (const float*)d_in[8];
    const float* A_log  = (const float*)d_in[9];
    const float* Dp     = (const float*)d_in[10];
    const float* W_out  = (const float*)d_in[11];
    float* out = (float*)d_out;

    // fp32 segments: 135,790,592 B
    float* xz    = (float*)d_ws;                          // 4096*4096
    float* uc    = xz    + (size_t)NTOK * 2 * D_INNER;    // 4096*2048
    float* dbc   = uc    + (size_t)NTOK * D_INNER;        // 4096*96
    float* delta = dbc   + (size_t)NTOK * 96;             // 4096*2048
    // bf16 (short) region: 20 Mi shorts = 41,943,040 B, phase-reused
    short* s0    = (short*)(delta + (size_t)NTOK * D_INNER);
    short* nh    = s0;                                    // phase A
    short* nl    = nh   + (size_t)NTOK * D_MODEL;
    short* wiTh  = nl   + (size_t)NTOK * D_MODEL;
    short* wiTl  = wiTh + (size_t)(2 * D_INNER) * D_MODEL;
    short* ygh   = s0;                                    // phase B (aliases A)
    short* ygl   = ygh  + (size_t)NTOK * D_INNER;
    short* woTh  = ygl  + (size_t)NTOK * D_INNER;
    short* woTl  = woTh + (size_t)D_MODEL * D_INNER;
    // scan carries: 2 x 8 MiB after the bf16 region
    float* carry_A = (float*)(s0 + (size_t)20971520);
    float* carry_h = carry_A + (size_t)2 * D_INNER * D_STATE * SCH;

    size_t needed_base = (size_t)135790592 + (size_t)41943040;
    size_t needed_fast = needed_base + (size_t)2 * 2 * D_INNER * D_STATE * SCH * 4;
    if (ws_size < needed_base) return;   // clean mismatch instead of OOB fault
    bool fast_scan = (ws_size >= needed_fast);

    // 0. weight transpose+split
    cvtT_k<<<dim3(2 * D_INNER / 64, D_MODEL / 64), 256, 0, stream>>>(W_in, wiTh, wiTl, D_MODEL, 2 * D_INNER);
    cvtT_k<<<dim3(D_MODEL / 64, D_INNER / 64), 256, 0, stream>>>(W_out, woTh, woTl, D_INNER, D_MODEL);
    // 1. LayerNorm -> bf16 hi/lo
    ln_kernel<<<NTOK, 256, 0, stream>>>(x, ln_w, ln_b, nh, nl);
    // 2. xz = normed @ W_in   (bf16x3 MFMA)
    mgemm_k<0><<<dim3(2 * D_INNER / 128, NTOK / 128), 256, 0, stream>>>(
        nh, nl, wiTh, wiTl, xz, 2 * D_INNER, D_MODEL, nullptr);
    // 3. depthwise conv + SiLU
    conv_silu_kernel<<<(NTOK * D_INNER) / 256, 256, 0, stream>>>(xz, conv_w, conv_b, uc);
    // 4. dbc = uc @ W_xproj
    sgemm64_k<<<dim3(2, NTOK / GBM), 256, 0, stream>>>(
        uc, D_INNER, W_xprj, 96, dbc, 96, 96, D_INNER);
    // 5. delta = softplus(dt @ W_dt + b_dt)
    sgemm128_k<1><<<dim3(D_INNER / TBN, NTOK / TBM), 256, 0, stream>>>(
        dbc, 96, W_dt, D_INNER, delta, D_INNER, DT_RANK, b_dt);
    // 6. selective scan + gating -> bf16 hi/lo
    if (fast_scan) {
        scan1_kernel<<<dim3(SCH, D_INNER / 16, 2), 256, 0, stream>>>(
            delta, uc, dbc, A_log, carry_A, carry_h);
        scan2_kernel<<<(2 * D_INNER * D_STATE) / 256, 256, 0, stream>>>(carry_A, carry_h);
        scan3_kernel<<<dim3(SCH, D_INNER / 16, 2), 256, 0, stream>>>(
            delta, uc, dbc, xz, A_log, Dp, carry_h, ygh, ygl);
    } else {
        scan_kernel<<<256, 256, 0, stream>>>(delta, uc, dbc, xz, A_log, Dp, ygh, ygl);
    }
    // 7. out = x + yg @ W_out  (bf16x3 MFMA)
    mgemm_k<2><<<dim3(D_MODEL / 128, NTOK / 128), 256, 0, stream>>>(
        ygh, ygl, woTh, woTl, out, D_MODEL, D_INNER, x);
}

// Round 7
// 639.261 us; speedup vs baseline: 2.8036x; 1.3274x over previous
//
#include <hip/hip_runtime.h>
#include <math.h>

#define D_MODEL 1024
#define D_INNER 2048
#define D_STATE 16
#define DT_RANK 64
#define LSEQ    2048
#define NTOK    4096   // B * L
#define SCH     32     // scan chunks
#define SCL     (LSEQ / SCH)   // 64 steps per chunk
#define LOG2E   1.44269504088896f

typedef short bf16x8 __attribute__((ext_vector_type(8)));
typedef float f32x4  __attribute__((ext_vector_type(4)));

__device__ __forceinline__ unsigned bf16_rne(float v) {
    unsigned u = __float_as_uint(v);
    return (u + 0x7FFFu + ((u >> 16) & 1u)) >> 16;
}
__device__ __forceinline__ void split_hi_lo(float v, short& h, short& l) {
    unsigned hb = bf16_rne(v);
    h = (short)hb;
    float r = v - __uint_as_float(hb << 16);
    l = (short)bf16_rne(r);
}

// ---------------------------------------------------------------- LayerNorm -> bf16 hi/lo
__global__ __launch_bounds__(256) void ln_kernel(const float* __restrict__ x,
                                                 const float* __restrict__ w,
                                                 const float* __restrict__ b,
                                                 short* __restrict__ nh,
                                                 short* __restrict__ nl)
{
    int t = blockIdx.x;
    const float4* xr = (const float4*)(x + (size_t)t * D_MODEL);
    float4 v = xr[threadIdx.x];
    float s  = v.x + v.y + v.z + v.w;
    float s2 = v.x*v.x + v.y*v.y + v.z*v.z + v.w*v.w;
    for (int off = 32; off > 0; off >>= 1) {
        s  += __shfl_down(s, off);
        s2 += __shfl_down(s2, off);
    }
    __shared__ float red[8];
    int wid = threadIdx.x >> 6, lane = threadIdx.x & 63;
    if (lane == 0) { red[wid] = s; red[4 + wid] = s2; }
    __syncthreads();
    if (threadIdx.x == 0) {
        float a = red[0] + red[1] + red[2] + red[3];
        float c = red[4] + red[5] + red[6] + red[7];
        red[0] = a * (1.f / (float)D_MODEL);
        red[4] = c * (1.f / (float)D_MODEL);
    }
    __syncthreads();
    float mu  = red[0];
    float var = red[4] - mu * mu;
    float rs  = rsqrtf(var + 1e-5f);
    float4 wv = ((const float4*)w)[threadIdx.x];
    float4 bv = ((const float4*)b)[threadIdx.x];
    float4 o;
    o.x = (v.x - mu) * rs * wv.x + bv.x;
    o.y = (v.y - mu) * rs * wv.y + bv.y;
    o.z = (v.z - mu) * rs * wv.z + bv.z;
    o.w = (v.w - mu) * rs * wv.w + bv.w;
    short4 h4, l4;
    split_hi_lo(o.x, h4.x, l4.x);
    split_hi_lo(o.y, h4.y, l4.y);
    split_hi_lo(o.z, h4.z, l4.z);
    split_hi_lo(o.w, h4.w, l4.w);
    size_t off = (size_t)t * D_MODEL + threadIdx.x * 4;
    *(short4*)&nh[off] = h4;
    *(short4*)&nl[off] = l4;
}

// -------------------------------------------- transpose + split fp32 W[R][C] -> [C][R] bf16 hi/lo
__global__ __launch_bounds__(256) void cvtT_k(const float* __restrict__ W,
                                              short* __restrict__ Th,
                                              short* __restrict__ Tl,
                                              int R, int Cc)
{
    __shared__ float t[64][65];
    int rr = threadIdx.x >> 4;
    int cc = (threadIdx.x & 15) << 2;
    int r0 = blockIdx.y * 64, c0 = blockIdx.x * 64;
#pragma unroll
    for (int s = 0; s < 4; ++s) {
        float4 v = *(const float4*)&W[(size_t)(r0 + rr + 16*s) * Cc + c0 + cc];
        t[rr+16*s][cc+0] = v.x; t[rr+16*s][cc+1] = v.y;
        t[rr+16*s][cc+2] = v.z; t[rr+16*s][cc+3] = v.w;
    }
    __syncthreads();
#pragma unroll
    for (int s = 0; s < 4; ++s) {
        int orow = rr + 16*s;
        short4 h4, l4;
        split_hi_lo(t[cc+0][orow], h4.x, l4.x);
        split_hi_lo(t[cc+1][orow], h4.y, l4.y);
        split_hi_lo(t[cc+2][orow], h4.z, l4.z);
        split_hi_lo(t[cc+3][orow], h4.w, l4.w);
        size_t off = (size_t)(c0 + orow) * R + r0 + cc;
        *(short4*)&Th[off] = h4;
        *(short4*)&Tl[off] = l4;
    }
}

// ---------------------------------------------------------------- bf16x3 MFMA GEMM
// C[M,N] = A[M,K] @ B[N,K]^T  via  Ah·Bh + Al·Bh + Ah·Bl, fp32 accum.
// Fragment-major LDS: staging writes and fragment reads are contiguous 1 KiB/wave.
template<int EPI>
__global__ __launch_bounds__(256) void mgemm_k(const short* __restrict__ Ah,
                                               const short* __restrict__ Al,
                                               const short* __restrict__ Bh,
                                               const short* __restrict__ Bl,
                                               float* __restrict__ C, int ldc,
                                               int K, const float* __restrict__ aux)
{
    __shared__ short lds[4][128 * 32];   // Ah | Al | Bh | Bl tiles

    int tid  = threadIdx.x;
    int w    = tid >> 6;
    int lane = tid & 63;
    int wr   = w >> 1, wc = w & 1;
    int row0 = blockIdx.y * 128;
    int col0 = blockIdx.x * 128;

    const short* gA = (w & 1) ? Al : Ah;
    const short* gB = (w & 1) ? Bl : Bh;
    const short* g  = (w & 2) ? gB : gA;
    int obase       = (w & 2) ? col0 : row0;
    const short* gtile = g + (size_t)obase * K;

    int srow  = lane >> 2;         // 0..15: row within 16-row group
    int skc   = lane & 3;          // 0..3 : k-chunk (8 shorts)
    int swoff = skc * 128 + srow * 8;

    int fr = lane & 15;
    int kg = lane >> 4;

    f32x4 acc[4][4] = {};

    for (int k0 = 0; k0 < K; k0 += 32) {
        bf16x8 stg[8];
#pragma unroll
        for (int i = 0; i < 8; ++i)
            stg[i] = *(const bf16x8*)(gtile + (size_t)(i * 16 + srow) * K + k0 + skc * 8);
        __syncthreads();
#pragma unroll
        for (int i = 0; i < 8; ++i)
            *(bf16x8*)&lds[w][i * 512 + swoff] = stg[i];
        __syncthreads();

        bf16x8 a_h[4], a_l[4], b_h[4], b_l[4];
#pragma unroll
        for (int m = 0; m < 4; ++m) {
            int ra = ((wr * 4 + m) * 4 + kg) * 128 + fr * 8;
            int rb = ((wc * 4 + m) * 4 + kg) * 128 + fr * 8;
            a_h[m] = *(const bf16x8*)&lds[0][ra];
            a_l[m] = *(const bf16x8*)&lds[1][ra];
            b_h[m] = *(const bf16x8*)&lds[2][rb];
            b_l[m] = *(const bf16x8*)&lds[3][rb];
        }
#pragma unroll
        for (int m = 0; m < 4; ++m)
#pragma unroll
            for (int n = 0; n < 4; ++n)
                acc[m][n] = __builtin_amdgcn_mfma_f32_16x16x32_bf16(a_h[m], b_h[n], acc[m][n], 0, 0, 0);
#pragma unroll
        for (int m = 0; m < 4; ++m)
#pragma unroll
            for (int n = 0; n < 4; ++n)
                acc[m][n] = __builtin_amdgcn_mfma_f32_16x16x32_bf16(a_l[m], b_h[n], acc[m][n], 0, 0, 0);
#pragma unroll
        for (int m = 0; m < 4; ++m)
#pragma unroll
            for (int n = 0; n < 4; ++n)
                acc[m][n] = __builtin_amdgcn_mfma_f32_16x16x32_bf16(a_h[m], b_l[n], acc[m][n], 0, 0, 0);
    }

    // C/D layout (m89-verified): col = lane&15, row = (lane>>4)*4 + reg
#pragma unroll
    for (int m = 0; m < 4; ++m) {
        int row = row0 + wr * 64 + m * 16 + kg * 4;
#pragma unroll
        for (int n = 0; n < 4; ++n) {
            int col = col0 + wc * 64 + n * 16 + fr;
#pragma unroll
            for (int j = 0; j < 4; ++j) {
                size_t off = (size_t)(row + j) * ldc + col;
                float v = acc[m][n][j];
                if (EPI == 2) v += aux[off];
                C[off] = v;
            }
        }
    }
}

// ---------------------------------------------------------------- SGEMM 128x128 fp32 (dt-proj)
#define TBM 128
#define TBN 128
#define TBK 16

template<int EPI>
__global__ __launch_bounds__(256) void sgemm128_k(const float* __restrict__ A, int lda,
                                                  const float* __restrict__ B, int ldb,
                                                  float* __restrict__ C, int ldc,
                                                  int K, const float* __restrict__ aux)
{
    __shared__ float As[TBK][TBM + 4];
    __shared__ float Bs[TBK][TBN + 4];

    int tid  = threadIdx.x;
    int row0 = blockIdx.y * TBM;
    int col0 = blockIdx.x * TBN;

    int arow = tid >> 2;
    int acol = (tid & 3) << 2;
    int brow = tid >> 5;
    int bcol = (tid & 31) << 2;

    int tr = tid >> 4;
    int tc = tid & 15;

    float acc[8][8] = {};

    for (int k0 = 0; k0 < K; k0 += TBK) {
        float4 a0 = *(const float4*)(A + (size_t)(row0 + arow)      * lda + k0 + acol);
        float4 a1 = *(const float4*)(A + (size_t)(row0 + arow + 64) * lda + k0 + acol);
        float4 b0 = *(const float4*)(B + (size_t)(k0 + brow)     * ldb + col0 + bcol);
        float4 b1 = *(const float4*)(B + (size_t)(k0 + brow + 8) * ldb + col0 + bcol);
        __syncthreads();
        As[acol + 0][arow] = a0.x;
        As[acol + 1][arow] = a0.y;
        As[acol + 2][arow] = a0.z;
        As[acol + 3][arow] = a0.w;
        As[acol + 0][arow + 64] = a1.x;
        As[acol + 1][arow + 64] = a1.y;
        As[acol + 2][arow + 64] = a1.z;
        As[acol + 3][arow + 64] = a1.w;
        *(float4*)&Bs[brow][bcol]     = b0;
        *(float4*)&Bs[brow + 8][bcol] = b1;
        __syncthreads();
#pragma unroll
        for (int kk = 0; kk < TBK; ++kk) {
            float4 x0 = *(const float4*)&As[kk][tr << 2];
            float4 x1 = *(const float4*)&As[kk][(tr << 2) + 64];
            float4 y0 = *(const float4*)&Bs[kk][tc << 2];
            float4 y1 = *(const float4*)&Bs[kk][(tc << 2) + 64];
            float xa[8] = {x0.x, x0.y, x0.z, x0.w, x1.x, x1.y, x1.z, x1.w};
            float yb[8] = {y0.x, y0.y, y0.z, y0.w, y1.x, y1.y, y1.z, y1.w};
#pragma unroll
            for (int i = 0; i < 8; ++i)
#pragma unroll
                for (int j = 0; j < 8; ++j)
                    acc[i][j] = fmaf(xa[i], yb[j], acc[i][j]);
        }
    }

#pragma unroll
    for (int ih = 0; ih < 2; ++ih) {
#pragma unroll
        for (int i = 0; i < 4; ++i) {
            int r = row0 + (tr << 2) + ih * 64 + i;
#pragma unroll
            for (int jh = 0; jh < 2; ++jh) {
                int c = col0 + (tc << 2) + jh * 64;
                size_t off = (size_t)r * ldc + c;
                float4 v = *(const float4*)&acc[ih * 4 + i][jh * 4];
                if (EPI == 1) {
                    float4 bb = *(const float4*)(aux + c);
                    float t0;
                    t0 = v.x + bb.x; v.x = fmaxf(t0, 0.f) + log1pf(expf(-fabsf(t0)));
                    t0 = v.y + bb.y; v.y = fmaxf(t0, 0.f) + log1pf(expf(-fabsf(t0)));
                    t0 = v.z + bb.z; v.z = fmaxf(t0, 0.f) + log1pf(expf(-fabsf(t0)));
                    t0 = v.w + bb.w; v.w = fmaxf(t0, 0.f) + log1pf(expf(-fabsf(t0)));
                } else if (EPI == 2) {
                    float4 rr = *(const float4*)(aux + off);
                    v.x += rr.x; v.y += rr.y; v.z += rr.z; v.w += rr.w;
                }
                *(float4*)(C + off) = v;
            }
        }
    }
}

// ---------------------------------------------------------------- SGEMM 64x64 (ragged N, xproj)
#define GBM 64
#define GBN 64
#define GBK 16

__global__ __launch_bounds__(256) void sgemm64_k(const float* __restrict__ A, int lda,
                                                 const float* __restrict__ B, int ldb,
                                                 float* __restrict__ C, int ldc,
                                                 int N, int K)
{
    __shared__ float As[GBK][GBM + 4];
    __shared__ float Bs[GBK][GBN + 4];

    int tid  = threadIdx.x;
    int row0 = blockIdx.y * GBM;
    int col0 = blockIdx.x * GBN;

    int ar = tid >> 2;
    int ac = (tid & 3) << 2;
    int br = tid >> 4;
    int bc = (tid & 15) << 2;

    int tr = tid >> 4;
    int tc = tid & 15;

    float acc[4][4] = {};

    for (int k0 = 0; k0 < K; k0 += GBK) {
        float4 av = *(const float4*)(A + (size_t)(row0 + ar) * lda + k0 + ac);
        float4 bv;
        int gcol = col0 + bc;
        if (gcol + 3 < N) {
            bv = *(const float4*)(B + (size_t)(k0 + br) * ldb + gcol);
        } else {
            const float* brow_p = B + (size_t)(k0 + br) * ldb;
            bv.x = (gcol + 0 < N) ? brow_p[gcol + 0] : 0.f;
            bv.y = (gcol + 1 < N) ? brow_p[gcol + 1] : 0.f;
            bv.z = (gcol + 2 < N) ? brow_p[gcol + 2] : 0.f;
            bv.w = (gcol + 3 < N) ? brow_p[gcol + 3] : 0.f;
        }
        __syncthreads();
        As[ac + 0][ar] = av.x;
        As[ac + 1][ar] = av.y;
        As[ac + 2][ar] = av.z;
        As[ac + 3][ar] = av.w;
        *(float4*)&Bs[br][bc] = bv;
        __syncthreads();
#pragma unroll
        for (int kk = 0; kk < GBK; ++kk) {
            float4 a = *(const float4*)&As[kk][tr << 2];
            float4 b = *(const float4*)&Bs[kk][tc << 2];
            acc[0][0] += a.x * b.x; acc[0][1] += a.x * b.y; acc[0][2] += a.x * b.z; acc[0][3] += a.x * b.w;
            acc[1][0] += a.y * b.x; acc[1][1] += a.y * b.y; acc[1][2] += a.y * b.z; acc[1][3] += a.y * b.w;
            acc[2][0] += a.z * b.x; acc[2][1] += a.z * b.y; acc[2][2] += a.z * b.z; acc[2][3] += a.z * b.w;
            acc[3][0] += a.w * b.x; acc[3][1] += a.w * b.y; acc[3][2] += a.w * b.z; acc[3][3] += a.w * b.w;
        }
    }

    int r0 = row0 + (tr << 2);
    int c0 = col0 + (tc << 2);
#pragma unroll
    for (int i = 0; i < 4; ++i) {
#pragma unroll
        for (int j = 0; j < 4; ++j) {
            int c = c0 + j;
            if (c < N) C[(size_t)(r0 + i) * ldc + c] = acc[i][j];
        }
    }
}

// ------------------------------------------------- depthwise causal conv + SiLU
__global__ __launch_bounds__(256) void conv_silu_kernel(const float* __restrict__ xz,
                                                        const float* __restrict__ conv_w,
                                                        const float* __restrict__ conv_b,
                                                        float* __restrict__ uc)
{
    int idx = blockIdx.x * 256 + threadIdx.x;
    if (idx >= NTOK * D_INNER) return;
    int d  = idx & (D_INNER - 1);
    int bl = idx >> 11;
    int l  = bl & (LSEQ - 1);
    float4 w = ((const float4*)conv_w)[d];
    float acc = conv_b[d];
    if (l >= 3) acc += w.x * xz[(size_t)(bl - 3) * (2 * D_INNER) + d];
    if (l >= 2) acc += w.y * xz[(size_t)(bl - 2) * (2 * D_INNER) + d];
    if (l >= 1) acc += w.z * xz[(size_t)(bl - 1) * (2 * D_INNER) + d];
    acc += w.w * xz[(size_t)bl * (2 * D_INNER) + d];
    uc[idx] = acc / (1.f + expf(-acc));
}

// ---------------------------------------------------------------- chunked scan (thread-per-channel)
// carries laid out [chunk][b][d][n] so all accesses are coalesced.
// pass 1: local scan from h=0; store (2^(sdv*A2[n]), h_end[n])
__global__ __launch_bounds__(256) void scan1_kernel(const float* __restrict__ delta,
                                                    const float* __restrict__ uc,
                                                    const float* __restrict__ dbc,
                                                    const float* __restrict__ A_log,
                                                    float* __restrict__ carry_A,
                                                    float* __restrict__ carry_h)
{
    __shared__ float Bs[SCL][16];
    int tid = threadIdx.x;
    int chunk = blockIdx.x, dg = blockIdx.y, b = blockIdx.z;
    int d = dg * 256 + tid;
    int rb0 = b * LSEQ + chunk * SCL;

    for (int i = tid; i < SCL * 16; i += 256) {
        int l = i >> 4, n = i & 15;
        Bs[l][n] = dbc[(size_t)(rb0 + l) * 96 + DT_RANK + n];
    }
    __syncthreads();

    float A2[16];
#pragma unroll
    for (int q = 0; q < 4; ++q) {
        float4 a = *(const float4*)&A_log[d * D_STATE + q * 4];
        A2[q*4+0] = -expf(a.x) * LOG2E;
        A2[q*4+1] = -expf(a.y) * LOG2E;
        A2[q*4+2] = -expf(a.z) * LOG2E;
        A2[q*4+3] = -expf(a.w) * LOG2E;
    }

    float h[16];
#pragma unroll
    for (int n = 0; n < 16; ++n) h[n] = 0.f;
    float sdv = 0.f;

    const float* dp = delta + (size_t)rb0 * D_INNER + d;
    const float* up = uc    + (size_t)rb0 * D_INNER + d;

    float dv = dp[0], uv = up[0];
    for (int l = 0; l < SCL; ++l) {
        float dvn = 0.f, uvn = 0.f;
        if (l + 1 < SCL) { dvn = dp[(l+1) * D_INNER]; uvn = up[(l+1) * D_INNER]; }
        float du = dv * uv;
        sdv += dv;
#pragma unroll
        for (int q = 0; q < 4; ++q) {
            float4 bq = *(const float4*)&Bs[l][q * 4];
            h[q*4+0] = fmaf(exp2f(dv * A2[q*4+0]), h[q*4+0], du * bq.x);
            h[q*4+1] = fmaf(exp2f(dv * A2[q*4+1]), h[q*4+1], du * bq.y);
            h[q*4+2] = fmaf(exp2f(dv * A2[q*4+2]), h[q*4+2], du * bq.z);
            h[q*4+3] = fmaf(exp2f(dv * A2[q*4+3]), h[q*4+3], du * bq.w);
        }
        dv = dvn; uv = uvn;
    }

    size_t cb = (((size_t)chunk * 2 + b) * D_INNER + d) * D_STATE;
#pragma unroll
    for (int q = 0; q < 4; ++q) {
        float4 ap, hh;
        ap.x = exp2f(sdv * A2[q*4+0]); ap.y = exp2f(sdv * A2[q*4+1]);
        ap.z = exp2f(sdv * A2[q*4+2]); ap.w = exp2f(sdv * A2[q*4+3]);
        hh.x = h[q*4+0]; hh.y = h[q*4+1]; hh.z = h[q*4+2]; hh.w = h[q*4+3];
        *(float4*)&carry_A[cb + q * 4] = ap;
        *(float4*)&carry_h[cb + q * 4] = hh;
    }
}

// pass 2: combine over chunks; carry_h becomes h_START per chunk
__global__ __launch_bounds__(256) void scan2_kernel(const float* __restrict__ carry_A,
                                                    float* __restrict__ carry_h)
{
    int idx = blockIdx.x * 256 + threadIdx.x;   // b*32768 + d*16 + n
    float h = 0.f;
#pragma unroll
    for (int c = 0; c < SCH; ++c) {
        size_t a = (size_t)c * (2 * D_INNER * D_STATE) + idx;
        float Ap = carry_A[a];
        float he = carry_h[a];
        carry_h[a] = h;
        h = fmaf(Ap, h, he);
    }
}

// pass 3: re-scan with h_start; emit gated y (bf16 hi/lo)
__global__ __launch_bounds__(256) void scan3_kernel(const float* __restrict__ delta,
                                                    const float* __restrict__ uc,
                                                    const float* __restrict__ dbc,
                                                    const float* __restrict__ xz,
                                                    const float* __restrict__ A_log,
                                                    const float* __restrict__ Dp,
                                                    const float* __restrict__ carry_h,
                                                    short* __restrict__ ygh,
                                                    short* __restrict__ ygl)
{
    __shared__ float Bs[SCL][16];
    __shared__ float Cs[SCL][16];
    int tid = threadIdx.x;
    int chunk = blockIdx.x, dg = blockIdx.y, b = blockIdx.z;
    int d = dg * 256 + tid;
    int rb0 = b * LSEQ + chunk * SCL;

    for (int i = tid; i < SCL * 32; i += 256) {
        int l = i >> 5, o = i & 31;
        float v = dbc[(size_t)(rb0 + l) * 96 + DT_RANK + o];
        if (o < 16) Bs[l][o] = v; else Cs[l][o - 16] = v;
    }
    __syncthreads();

    float A2[16];
#pragma unroll
    for (int q = 0; q < 4; ++q) {
        float4 a = *(const float4*)&A_log[d * D_STATE + q * 4];
        A2[q*4+0] = -expf(a.x) * LOG2E;
        A2[q*4+1] = -expf(a.y) * LOG2E;
        A2[q*4+2] = -expf(a.z) * LOG2E;
        A2[q*4+3] = -expf(a.w) * LOG2E;
    }
    float Dv = Dp[d];

    float h[16];
    size_t cb = (((size_t)chunk * 2 + b) * D_INNER + d) * D_STATE;
#pragma unroll
    for (int q = 0; q < 4; ++q) {
        float4 hh = *(const float4*)&carry_h[cb + q * 4];
        h[q*4+0] = hh.x; h[q*4+1] = hh.y; h[q*4+2] = hh.z; h[q*4+3] = hh.w;
    }

    const float* dp = delta + (size_t)rb0 * D_INNER + d;
    const float* up = uc    + (size_t)rb0 * D_INNER + d;
    const float* zp = xz    + (size_t)rb0 * (2 * D_INNER) + D_INNER + d;
    short* yhp = ygh + (size_t)rb0 * D_INNER + d;
    short* ylp = ygl + (size_t)rb0 * D_INNER + d;

    float dv = dp[0], uv = up[0], zv = zp[0];
    for (int l = 0; l < SCL; ++l) {
        float dvn = 0.f, uvn = 0.f, zvn = 0.f;
        if (l + 1 < SCL) {
            dvn = dp[(l+1) * D_INNER];
            uvn = up[(l+1) * D_INNER];
            zvn = zp[(size_t)(l+1) * (2 * D_INNER)];
        }
        float du = dv * uv;
        float y = 0.f;
#pragma unroll
        for (int q = 0; q < 4; ++q) {
            float4 bq = *(const float4*)&Bs[l][q * 4];
            float4 cq = *(const float4*)&Cs[l][q * 4];
            h[q*4+0] = fmaf(exp2f(dv * A2[q*4+0]), h[q*4+0], du * bq.x);
            h[q*4+1] = fmaf(exp2f(dv * A2[q*4+1]), h[q*4+1], du * bq.y);
            h[q*4+2] = fmaf(exp2f(dv * A2[q*4+2]), h[q*4+2], du * bq.z);
            h[q*4+3] = fmaf(exp2f(dv * A2[q*4+3]), h[q*4+3], du * bq.w);
            y = fmaf(h[q*4+0], cq.x, y);
            y = fmaf(h[q*4+1], cq.y, y);
            y = fmaf(h[q*4+2], cq.z, y);
            y = fmaf(h[q*4+3], cq.w, y);
        }
        float yd  = fmaf(uv, Dv, y);
        float val = yd * (zv / (1.f + expf(-zv)));
        short hh, ll;
        split_hi_lo(val, hh, ll);
        yhp[l * D_INNER] = hh;
        ylp[l * D_INNER] = ll;
        dv = dvn; uv = uvn; zv = zvn;
    }
}

// ---------------------------------------------------------------- serial scan (ws fallback)
__global__ __launch_bounds__(256) void scan_kernel(const float* __restrict__ delta,
                                                   const float* __restrict__ uc,
                                                   const float* __restrict__ dbc,
                                                   const float* __restrict__ xz,
                                                   const float* __restrict__ A_log,
                                                   const float* __restrict__ Dp,
                                                   short* __restrict__ ygh,
                                                   short* __restrict__ ygl)
{
    int tid = threadIdx.x;
    int g = tid >> 4, n = tid & 15;
    int bid = blockIdx.x;
    int b = bid >> 7;
    int d = (bid & 127) * 16 + g;
    float Adn = -expf(A_log[d * D_STATE + n]);
    float Dv  = Dp[d];
    float h = 0.f;
    size_t rowb = (size_t)b * LSEQ;

    float dv = delta[rowb * D_INNER + d];
    float uv = uc[rowb * D_INNER + d];
    float Bv = dbc[rowb * 96 + DT_RANK + n];
    float Cv = dbc[rowb * 96 + DT_RANK + D_STATE + n];

    for (int l = 0; l < LSEQ; ++l) {
        float dv_n = 0.f, uv_n = 0.f, Bv_n = 0.f, Cv_n = 0.f;
        if (l + 1 < LSEQ) {
            size_t r = rowb + l + 1;
            dv_n = delta[r * D_INNER + d];
            uv_n = uc[r * D_INNER + d];
            Bv_n = dbc[r * 96 + DT_RANK + n];
            Cv_n = dbc[r * 96 + DT_RANK + D_STATE + n];
        }
        float dA = expf(dv * Adn);
        h = fmaf(dA, h, dv * uv * Bv);
        float p = h * Cv;
        p += __shfl_xor(p, 1);
        p += __shfl_xor(p, 2);
        p += __shfl_xor(p, 4);
        p += __shfl_xor(p, 8);
        if (n == 0) {
            size_t r = rowb + l;
            float zv = xz[r * (2 * D_INNER) + D_INNER + d];
            float y  = fmaf(uv, Dv, p);
            float val = y * (zv / (1.f + expf(-zv)));
            short hh, ll;
            split_hi_lo(val, hh, ll);
            ygh[r * D_INNER + d] = hh;
            ygl[r * D_INNER + d] = ll;
        }
        dv = dv_n; uv = uv_n; Bv = Bv_n; Cv = Cv_n;
    }
}

// ---------------------------------------------------------------- launch
extern "C" void kernel_launch(void* const* d_in, const int* in_sizes, int n_in,
                              void* d_out, int out_size, void* d_ws, size_t ws_size,
                              hipStream_t stream)
{
    const float* x      = (const float*)d_in[0];
    const float* ln_w   = (const float*)d_in[1];
    const float* ln_b   = (const float*)d_in[2];
    const float* W_in   = (const float*)d_in[3];
    const float* conv_w = (const float*)d_in[4];
    const float* conv_b = (const float*)d_in[5];
    const float* W_xprj = (const float*)d_in[6];
    const float* W_dt   = (const float*)d_in[7];
    const float* b_dt   = (const float*)d_in[8];
    const float* A_log  = (const float*)d_in[9];
    const float* Dp     = (const float*)d_in[10];
    const float* W_out  = (const float*)d_in[11];
    float* out = (float*)d_out;

    // fp32 segments: 135,790,592 B
    float* xz    = (float*)d_ws;                          // 4096*4096
    float* uc    = xz    + (size_t)NTOK * 2 * D_INNER;    // 4096*2048
    float* dbc   = uc    + (size_t)NTOK * D_INNER;        // 4096*96
    float* delta = dbc   + (size_t)NTOK * 96;             // 4096*2048
    // bf16 (short) region: 20 Mi shorts, phase-reused
    short* s0    = (short*)(delta + (size_t)NTOK * D_INNER);
    short* nh    = s0;                                    // phase A
    short* nl    = nh   + (size_t)NTOK * D_MODEL;
    short* wiTh  = nl   + (size_t)NTOK * D_MODEL;
    short* wiTl  = wiTh + (size_t)(2 * D_INNER) * D_MODEL;
    short* ygh   = s0;                                    // phase B (aliases A)
    short* ygl   = ygh  + (size_t)NTOK * D_INNER;
    short* woTh  = ygl  + (size_t)NTOK * D_INNER;
    short* woTl  = woTh + (size_t)D_MODEL * D_INNER;
    // scan carries: 2 x 8 MiB after the bf16 region
    float* carry_A = (float*)(s0 + (size_t)20971520);
    float* carry_h = carry_A + (size_t)2 * D_INNER * D_STATE * SCH;

    size_t needed_base = (size_t)135790592 + (size_t)41943040;
    size_t needed_fast = needed_base + (size_t)2 * 2 * D_INNER * D_STATE * SCH * 4;
    if (ws_size < needed_base) return;
    bool fast_scan = (ws_size >= needed_fast);

    // 0. weight transpose+split
    cvtT_k<<<dim3(2 * D_INNER / 64, D_MODEL / 64), 256, 0, stream>>>(W_in, wiTh, wiTl, D_MODEL, 2 * D_INNER);
    cvtT_k<<<dim3(D_MODEL / 64, D_INNER / 64), 256, 0, stream>>>(W_out, woTh, woTl, D_INNER, D_MODEL);
    // 1. LayerNorm -> bf16 hi/lo
    ln_kernel<<<NTOK, 256, 0, stream>>>(x, ln_w, ln_b, nh, nl);
    // 2. xz = normed @ W_in   (bf16x3 MFMA)
    mgemm_k<0><<<dim3(2 * D_INNER / 128, NTOK / 128), 256, 0, stream>>>(
        nh, nl, wiTh, wiTl, xz, 2 * D_INNER, D_MODEL, nullptr);
    // 3. depthwise conv + SiLU
    conv_silu_kernel<<<(NTOK * D_INNER) / 256, 256, 0, stream>>>(xz, conv_w, conv_b, uc);
    // 4. dbc = uc @ W_xproj
    sgemm64_k<<<dim3(2, NTOK / GBM), 256, 0, stream>>>(
        uc, D_INNER, W_xprj, 96, dbc, 96, 96, D_INNER);
    // 5. delta = softplus(dt @ W_dt + b_dt)
    sgemm128_k<1><<<dim3(D_INNER / TBN, NTOK / TBM), 256, 0, stream>>>(
        dbc, 96, W_dt, D_INNER, delta, D_INNER, DT_RANK, b_dt);
    // 6. selective scan + gating -> bf16 hi/lo
    if (fast_scan) {
        scan1_kernel<<<dim3(SCH, D_INNER / 256, 2), 256, 0, stream>>>(
            delta, uc, dbc, A_log, carry_A, carry_h);
        scan2_kernel<<<(2 * D_INNER * D_STATE) / 256, 256, 0, stream>>>(carry_A, carry_h);
        scan3_kernel<<<dim3(SCH, D_INNER / 256, 2), 256, 0, stream>>>(
            delta, uc, dbc, xz, A_log, Dp, carry_h, ygh, ygl);
    } else {
        scan_kernel<<<256, 256, 0, stream>>>(delta, uc, dbc, xz, A_log, Dp, ygh, ygl);
    }
    // 7. out = x + yg @ W_out  (bf16x3 MFMA)
    mgemm_k<2><<<dim3(D_MODEL / 128, NTOK / 128), 256, 0, stream>>>(
        ygh, ygl, woTh, woTl, out, D_MODEL, D_INNER, x);
}

// Round 9
// 599.029 us; speedup vs baseline: 2.9919x; 1.0672x over previous
//
#include <hip/hip_runtime.h>
#include <math.h>

#define D_MODEL 1024
#define D_INNER 2048
#define D_STATE 16
#define DT_RANK 64
#define LSEQ    2048
#define NTOK    4096   // B * L
#define SCH     32     // scan chunks
#define SCL     (LSEQ / SCH)   // 64 steps per chunk
#define LOG2E   1.44269504088896f
#define XKS     4      // xproj K-splits
#define XKC     (D_INNER / XKS)

typedef short bf16x8 __attribute__((ext_vector_type(8)));
typedef float f32x4  __attribute__((ext_vector_type(4)));

__device__ __forceinline__ unsigned bf16_rne(float v) {
    unsigned u = __float_as_uint(v);
    return (u + 0x7FFFu + ((u >> 16) & 1u)) >> 16;
}
__device__ __forceinline__ void split_hi_lo(float v, short& h, short& l) {
    unsigned hb = bf16_rne(v);
    h = (short)hb;
    float r = v - __uint_as_float(hb << 16);
    l = (short)bf16_rne(r);
}

// ---------------------------------------------------------------- LayerNorm -> bf16 hi/lo
__global__ __launch_bounds__(256) void ln_kernel(const float* __restrict__ x,
                                                 const float* __restrict__ w,
                                                 const float* __restrict__ b,
                                                 short* __restrict__ nh,
                                                 short* __restrict__ nl)
{
    int t = blockIdx.x;
    const float4* xr = (const float4*)(x + (size_t)t * D_MODEL);
    float4 v = xr[threadIdx.x];
    float s  = v.x + v.y + v.z + v.w;
    float s2 = v.x*v.x + v.y*v.y + v.z*v.z + v.w*v.w;
    for (int off = 32; off > 0; off >>= 1) {
        s  += __shfl_down(s, off);
        s2 += __shfl_down(s2, off);
    }
    __shared__ float red[8];
    int wid = threadIdx.x >> 6, lane = threadIdx.x & 63;
    if (lane == 0) { red[wid] = s; red[4 + wid] = s2; }
    __syncthreads();
    if (threadIdx.x == 0) {
        float a = red[0] + red[1] + red[2] + red[3];
        float c = red[4] + red[5] + red[6] + red[7];
        red[0] = a * (1.f / (float)D_MODEL);
        red[4] = c * (1.f / (float)D_MODEL);
    }
    __syncthreads();
    float mu  = red[0];
    float var = red[4] - mu * mu;
    float rs  = rsqrtf(var + 1e-5f);
    float4 wv = ((const float4*)w)[threadIdx.x];
    float4 bv = ((const float4*)b)[threadIdx.x];
    float4 o;
    o.x = (v.x - mu) * rs * wv.x + bv.x;
    o.y = (v.y - mu) * rs * wv.y + bv.y;
    o.z = (v.z - mu) * rs * wv.z + bv.z;
    o.w = (v.w - mu) * rs * wv.w + bv.w;
    short4 h4, l4;
    split_hi_lo(o.x, h4.x, l4.x);
    split_hi_lo(o.y, h4.y, l4.y);
    split_hi_lo(o.z, h4.z, l4.z);
    split_hi_lo(o.w, h4.w, l4.w);
    size_t off = (size_t)t * D_MODEL + threadIdx.x * 4;
    *(short4*)&nh[off] = h4;
    *(short4*)&nl[off] = l4;
}

// -------------------------------------------- transpose + split fp32 W[R][C] -> [C][R] bf16 hi/lo
__global__ __launch_bounds__(256) void cvtT_k(const float* __restrict__ W,
                                              short* __restrict__ Th,
                                              short* __restrict__ Tl,
                                              int R, int Cc)
{
    __shared__ float t[64][65];
    int rr = threadIdx.x >> 4;
    int cc = (threadIdx.x & 15) << 2;
    int r0 = blockIdx.y * 64, c0 = blockIdx.x * 64;
#pragma unroll
    for (int s = 0; s < 4; ++s) {
        float4 v = *(const float4*)&W[(size_t)(r0 + rr + 16*s) * Cc + c0 + cc];
        t[rr+16*s][cc+0] = v.x; t[rr+16*s][cc+1] = v.y;
        t[rr+16*s][cc+2] = v.z; t[rr+16*s][cc+3] = v.w;
    }
    __syncthreads();
#pragma unroll
    for (int s = 0; s < 4; ++s) {
        int orow = rr + 16*s;
        short4 h4, l4;
        split_hi_lo(t[cc+0][orow], h4.x, l4.x);
        split_hi_lo(t[cc+1][orow], h4.y, l4.y);
        split_hi_lo(t[cc+2][orow], h4.z, l4.z);
        split_hi_lo(t[cc+3][orow], h4.w, l4.w);
        size_t off = (size_t)(c0 + orow) * R + r0 + cc;
        *(short4*)&Th[off] = h4;
        *(short4*)&Tl[off] = l4;
    }
}

// ---------------------------------------------------------------- bf16x3 MFMA GEMM
// Fragment-major LDS; staging via global_load_lds (linear dest, re-indexed
// per-lane source: kc=lane>>4, r=lane&15 — rule 21) or reg-staging fallback.
template<int EPI>
__global__ __launch_bounds__(256) void mgemm_k(const short* __restrict__ Ah,
                                               const short* __restrict__ Al,
                                               const short* __restrict__ Bh,
                                               const short* __restrict__ Bl,
                                               float* __restrict__ C, int ldc,
                                               int K, const float* __restrict__ aux)
{
    __shared__ short lds[4][128 * 32];   // Ah | Al | Bh | Bl tiles

    int tid  = threadIdx.x;
    int w    = tid >> 6;
    int lane = tid & 63;
    int wr   = w >> 1, wc = w & 1;
    int row0 = blockIdx.y * 128;
    int col0 = blockIdx.x * 128;

    const short* gA = (w & 1) ? Al : Ah;
    const short* gB = (w & 1) ? Bl : Bh;
    const short* g  = (w & 2) ? gB : gA;
    int obase       = (w & 2) ? col0 : row0;
    const short* gtile = g + (size_t)obase * K;

    int fr = lane & 15;
    int kg = lane >> 4;

    f32x4 acc[4][4] = {};

    for (int k0 = 0; k0 < K; k0 += 32) {
#if __has_builtin(__builtin_amdgcn_global_load_lds)
        __syncthreads();   // previous tile's readers done
#pragma unroll
        for (int i = 0; i < 8; ++i) {
            // lane lan: LDS slot lan*16B = kc*256B + r*16B with kc=lan>>4, r=lan&15
            const short* src = gtile + (size_t)(i * 16 + fr) * K + k0 + kg * 8;
            __builtin_amdgcn_global_load_lds(
                (const __attribute__((address_space(1))) void*)src,
                (__attribute__((address_space(3))) void*)&lds[w][i * 512],
                16, 0, 0);
        }
        __syncthreads();   // vmcnt drained by compiler before barrier
#else
        int srow  = lane >> 2;
        int skc   = lane & 3;
        int swoff = skc * 128 + srow * 8;
        bf16x8 stg[8];
#pragma unroll
        for (int i = 0; i < 8; ++i)
            stg[i] = *(const bf16x8*)(gtile + (size_t)(i * 16 + srow) * K + k0 + skc * 8);
        __syncthreads();
#pragma unroll
        for (int i = 0; i < 8; ++i)
            *(bf16x8*)&lds[w][i * 512 + swoff] = stg[i];
        __syncthreads();
#endif

        bf16x8 a_h[4], a_l[4], b_h[4], b_l[4];
#pragma unroll
        for (int m = 0; m < 4; ++m) {
            int ra = ((wr * 4 + m) * 4 + kg) * 128 + fr * 8;
            int rb = ((wc * 4 + m) * 4 + kg) * 128 + fr * 8;
            a_h[m] = *(const bf16x8*)&lds[0][ra];
            a_l[m] = *(const bf16x8*)&lds[1][ra];
            b_h[m] = *(const bf16x8*)&lds[2][rb];
            b_l[m] = *(const bf16x8*)&lds[3][rb];
        }
#pragma unroll
        for (int m = 0; m < 4; ++m)
#pragma unroll
            for (int n = 0; n < 4; ++n)
                acc[m][n] = __builtin_amdgcn_mfma_f32_16x16x32_bf16(a_h[m], b_h[n], acc[m][n], 0, 0, 0);
#pragma unroll
        for (int m = 0; m < 4; ++m)
#pragma unroll
            for (int n = 0; n < 4; ++n)
                acc[m][n] = __builtin_amdgcn_mfma_f32_16x16x32_bf16(a_l[m], b_h[n], acc[m][n], 0, 0, 0);
#pragma unroll
        for (int m = 0; m < 4; ++m)
#pragma unroll
            for (int n = 0; n < 4; ++n)
                acc[m][n] = __builtin_amdgcn_mfma_f32_16x16x32_bf16(a_h[m], b_l[n], acc[m][n], 0, 0, 0);
    }

    // C/D layout (m89-verified): col = lane&15, row = (lane>>4)*4 + reg
#pragma unroll
    for (int m = 0; m < 4; ++m) {
        int row = row0 + wr * 64 + m * 16 + kg * 4;
#pragma unroll
        for (int n = 0; n < 4; ++n) {
            int col = col0 + wc * 64 + n * 16 + fr;
#pragma unroll
            for (int j = 0; j < 4; ++j) {
                size_t off = (size_t)(row + j) * ldc + col;
                float v = acc[m][n][j];
                if (EPI == 2) v += aux[off];
                C[off] = v;
            }
        }
    }
}

// ---------------------------------------------------------------- SGEMM 128x128 fp32 (dt-proj)
#define TBM 128
#define TBN 128
#define TBK 16

template<int EPI>
__global__ __launch_bounds__(256) void sgemm128_k(const float* __restrict__ A, int lda,
                                                  const float* __restrict__ B, int ldb,
                                                  float* __restrict__ C, int ldc,
                                                  int K, const float* __restrict__ aux)
{
    __shared__ float As[TBK][TBM + 4];
    __shared__ float Bs[TBK][TBN + 4];

    int tid  = threadIdx.x;
    int row0 = blockIdx.y * TBM;
    int col0 = blockIdx.x * TBN;

    int arow = tid >> 2;
    int acol = (tid & 3) << 2;
    int brow = tid >> 5;
    int bcol = (tid & 31) << 2;

    int tr = tid >> 4;
    int tc = tid & 15;

    float acc[8][8] = {};

    for (int k0 = 0; k0 < K; k0 += TBK) {
        float4 a0 = *(const float4*)(A + (size_t)(row0 + arow)      * lda + k0 + acol);
        float4 a1 = *(const float4*)(A + (size_t)(row0 + arow + 64) * lda + k0 + acol);
        float4 b0 = *(const float4*)(B + (size_t)(k0 + brow)     * ldb + col0 + bcol);
        float4 b1 = *(const float4*)(B + (size_t)(k0 + brow + 8) * ldb + col0 + bcol);
        __syncthreads();
        As[acol + 0][arow] = a0.x;
        As[acol + 1][arow] = a0.y;
        As[acol + 2][arow] = a0.z;
        As[acol + 3][arow] = a0.w;
        As[acol + 0][arow + 64] = a1.x;
        As[acol + 1][arow + 64] = a1.y;
        As[acol + 2][arow + 64] = a1.z;
        As[acol + 3][arow + 64] = a1.w;
        *(float4*)&Bs[brow][bcol]     = b0;
        *(float4*)&Bs[brow + 8][bcol] = b1;
        __syncthreads();
#pragma unroll
        for (int kk = 0; kk < TBK; ++kk) {
            float4 x0 = *(const float4*)&As[kk][tr << 2];
            float4 x1 = *(const float4*)&As[kk][(tr << 2) + 64];
            float4 y0 = *(const float4*)&Bs[kk][tc << 2];
            float4 y1 = *(const float4*)&Bs[kk][(tc << 2) + 64];
            float xa[8] = {x0.x, x0.y, x0.z, x0.w, x1.x, x1.y, x1.z, x1.w};
            float yb[8] = {y0.x, y0.y, y0.z, y0.w, y1.x, y1.y, y1.z, y1.w};
#pragma unroll
            for (int i = 0; i < 8; ++i)
#pragma unroll
                for (int j = 0; j < 8; ++j)
                    acc[i][j] = fmaf(xa[i], yb[j], acc[i][j]);
        }
    }

#pragma unroll
    for (int ih = 0; ih < 2; ++ih) {
#pragma unroll
        for (int i = 0; i < 4; ++i) {
            int r = row0 + (tr << 2) + ih * 64 + i;
#pragma unroll
            for (int jh = 0; jh < 2; ++jh) {
                int c = col0 + (tc << 2) + jh * 64;
                size_t off = (size_t)r * ldc + c;
                float4 v = *(const float4*)&acc[ih * 4 + i][jh * 4];
                if (EPI == 1) {
                    float4 bb = *(const float4*)(aux + c);
                    float t0;
                    t0 = v.x + bb.x; v.x = fmaxf(t0, 0.f) + log1pf(expf(-fabsf(t0)));
                    t0 = v.y + bb.y; v.y = fmaxf(t0, 0.f) + log1pf(expf(-fabsf(t0)));
                    t0 = v.z + bb.z; v.z = fmaxf(t0, 0.f) + log1pf(expf(-fabsf(t0)));
                    t0 = v.w + bb.w; v.w = fmaxf(t0, 0.f) + log1pf(expf(-fabsf(t0)));
                } else if (EPI == 2) {
                    float4 rr = *(const float4*)(aux + off);
                    v.x += rr.x; v.y += rr.y; v.z += rr.z; v.w += rr.w;
                }
                *(float4*)(C + off) = v;
            }
        }
    }
}

// ---------------------------------------------------------------- xproj skinny GEMM, split-K
// part[ks][row][96] = uc[row, ks*XKC:+XKC] @ W_xproj[ks*XKC:+XKC, :96]
// float4 A loads (per-thread contiguous); W reads wave-uniform.
__global__ __launch_bounds__(256) void xproj_k(const float* __restrict__ A,
                                               const float* __restrict__ W,
                                               float* __restrict__ part)
{
    int row = blockIdx.x * 256 + threadIdx.x;   // 0..4095
    int cg  = blockIdx.y;                        // 0..11 (8 cols)
    int ks  = blockIdx.z;                        // 0..XKS-1
    const float4* a4 = (const float4*)(A + (size_t)row * D_INNER + ks * XKC);
    const float* w = W + (size_t)ks * XKC * 96 + cg * 8;
    float acc[8] = {};
#pragma unroll 2
    for (int k4 = 0; k4 < XKC / 4; ++k4) {
        float4 av = a4[k4];
        const float* wk = w + (size_t)k4 * 4 * 96;
        float a0 = av.x, a1 = av.y, a2 = av.z, a3 = av.w;
#pragma unroll
        for (int kk = 0; kk < 4; ++kk) {
            float ak = (kk == 0) ? a0 : (kk == 1) ? a1 : (kk == 2) ? a2 : a3;
            float4 w0 = *(const float4*)(wk + (size_t)kk * 96);
            float4 w1 = *(const float4*)(wk + (size_t)kk * 96 + 4);
            acc[0] = fmaf(ak, w0.x, acc[0]);
            acc[1] = fmaf(ak, w0.y, acc[1]);
            acc[2] = fmaf(ak, w0.z, acc[2]);
            acc[3] = fmaf(ak, w0.w, acc[3]);
            acc[4] = fmaf(ak, w1.x, acc[4]);
            acc[5] = fmaf(ak, w1.y, acc[5]);
            acc[6] = fmaf(ak, w1.z, acc[6]);
            acc[7] = fmaf(ak, w1.w, acc[7]);
        }
    }
    float* p = part + ((size_t)ks * NTOK + row) * 96 + cg * 8;
    *(float4*)p       = *(float4*)&acc[0];
    *(float4*)(p + 4) = *(float4*)&acc[4];
}

__global__ __launch_bounds__(256) void xreduce_k(const float* __restrict__ part,
                                                 float* __restrict__ dbc)
{
    int i = blockIdx.x * 256 + threadIdx.x;     // over 4096*96/4 = 98304 float4s
    const float4* p = (const float4*)part;
    float4 s0 = p[i];
    float4 s1 = p[i + 98304];
    float4 s2 = p[i + 2 * 98304];
    float4 s3 = p[i + 3 * 98304];
    float4 s;
    s.x = (s0.x + s1.x) + (s2.x + s3.x);
    s.y = (s0.y + s1.y) + (s2.y + s3.y);
    s.z = (s0.z + s1.z) + (s2.z + s3.z);
    s.w = (s0.w + s1.w) + (s2.w + s3.w);
    ((float4*)dbc)[i] = s;
}

// ------------------------------------------------- depthwise causal conv + SiLU
__global__ __launch_bounds__(256) void conv_silu_kernel(const float* __restrict__ xz,
                                                        const float* __restrict__ conv_w,
                                                        const float* __restrict__ conv_b,
                                                        float* __restrict__ uc)
{
    int idx = blockIdx.x * 256 + threadIdx.x;
    if (idx >= NTOK * D_INNER) return;
    int d  = idx & (D_INNER - 1);
    int bl = idx >> 11;
    int l  = bl & (LSEQ - 1);
    float4 w = ((const float4*)conv_w)[d];
    float acc = conv_b[d];
    if (l >= 3) acc += w.x * xz[(size_t)(bl - 3) * (2 * D_INNER) + d];
    if (l >= 2) acc += w.y * xz[(size_t)(bl - 2) * (2 * D_INNER) + d];
    if (l >= 1) acc += w.z * xz[(size_t)(bl - 1) * (2 * D_INNER) + d];
    acc += w.w * xz[(size_t)bl * (2 * D_INNER) + d];
    uc[idx] = acc / (1.f + expf(-acc));
}

// ---------------------------------------------------------------- chunked scan (thread-per-channel)
__global__ __launch_bounds__(256) void scan1_kernel(const float* __restrict__ delta,
                                                    const float* __restrict__ uc,
                                                    const float* __restrict__ dbc,
                                                    const float* __restrict__ A_log,
                                                    float* __restrict__ carry_A,
                                                    float* __restrict__ carry_h)
{
    __shared__ float Bs[SCL][16];
    int tid = threadIdx.x;
    int chunk = blockIdx.x, dg = blockIdx.y, b = blockIdx.z;
    int d = dg * 256 + tid;
    int rb0 = b * LSEQ + chunk * SCL;

    for (int i = tid; i < SCL * 16; i += 256) {
        int l = i >> 4, n = i & 15;
        Bs[l][n] = dbc[(size_t)(rb0 + l) * 96 + DT_RANK + n];
    }
    __syncthreads();

    float A2[16];
#pragma unroll
    for (int q = 0; q < 4; ++q) {
        float4 a = *(const float4*)&A_log[d * D_STATE + q * 4];
        A2[q*4+0] = -expf(a.x) * LOG2E;
        A2[q*4+1] = -expf(a.y) * LOG2E;
        A2[q*4+2] = -expf(a.z) * LOG2E;
        A2[q*4+3] = -expf(a.w) * LOG2E;
    }

    float h[16];
#pragma unroll
    for (int n = 0; n < 16; ++n) h[n] = 0.f;
    float sdv = 0.f;

    const float* dp = delta + (size_t)rb0 * D_INNER + d;
    const float* up = uc    + (size_t)rb0 * D_INNER + d;

    float dv = dp[0], uv = up[0];
    for (int l = 0; l < SCL; ++l) {
        float dvn = 0.f, uvn = 0.f;
        if (l + 1 < SCL) { dvn = dp[(l+1) * D_INNER]; uvn = up[(l+1) * D_INNER]; }
        float du = dv * uv;
        sdv += dv;
#pragma unroll
        for (int q = 0; q < 4; ++q) {
            float4 bq = *(const float4*)&Bs[l][q * 4];
            h[q*4+0] = fmaf(exp2f(dv * A2[q*4+0]), h[q*4+0], du * bq.x);
            h[q*4+1] = fmaf(exp2f(dv * A2[q*4+1]), h[q*4+1], du * bq.y);
            h[q*4+2] = fmaf(exp2f(dv * A2[q*4+2]), h[q*4+2], du * bq.z);
            h[q*4+3] = fmaf(exp2f(dv * A2[q*4+3]), h[q*4+3], du * bq.w);
        }
        dv = dvn; uv = uvn;
    }

    size_t cb = (((size_t)chunk * 2 + b) * D_INNER + d) * D_STATE;
#pragma unroll
    for (int q = 0; q < 4; ++q) {
        float4 ap, hh;
        ap.x = exp2f(sdv * A2[q*4+0]); ap.y = exp2f(sdv * A2[q*4+1]);
        ap.z = exp2f(sdv * A2[q*4+2]); ap.w = exp2f(sdv * A2[q*4+3]);
        hh.x = h[q*4+0]; hh.y = h[q*4+1]; hh.z = h[q*4+2]; hh.w = h[q*4+3];
        *(float4*)&carry_A[cb + q * 4] = ap;
        *(float4*)&carry_h[cb + q * 4] = hh;
    }
}

__global__ __launch_bounds__(256) void scan2_kernel(const float* __restrict__ carry_A,
                                                    float* __restrict__ carry_h)
{
    int idx = blockIdx.x * 256 + threadIdx.x;
    float h = 0.f;
#pragma unroll
    for (int c = 0; c < SCH; ++c) {
        size_t a = (size_t)c * (2 * D_INNER * D_STATE) + idx;
        float Ap = carry_A[a];
        float he = carry_h[a];
        carry_h[a] = h;
        h = fmaf(Ap, h, he);
    }
}

__global__ __launch_bounds__(256) void scan3_kernel(const float* __restrict__ delta,
                                                    const float* __restrict__ uc,
                                                    const float* __restrict__ dbc,
                                                    const float* __restrict__ xz,
                                                    const float* __restrict__ A_log,
                                                    const float* __restrict__ Dp,
                                                    const float* __restrict__ carry_h,
                                                    short* __restrict__ ygh,
                                                    short* __restrict__ ygl)
{
    __shared__ float Bs[SCL][16];
    __shared__ float Cs[SCL][16];
    int tid = threadIdx.x;
    int chunk = blockIdx.x, dg = blockIdx.y, b = blockIdx.z;
    int d = dg * 256 + tid;
    int rb0 = b * LSEQ + chunk * SCL;

    for (int i = tid; i < SCL * 32; i += 256) {
        int l = i >> 5, o = i & 31;
        float v = dbc[(size_t)(rb0 + l) * 96 + DT_RANK + o];
        if (o < 16) Bs[l][o] = v; else Cs[l][o - 16] = v;
    }
    __syncthreads();

    float A2[16];
#pragma unroll
    for (int q = 0; q < 4; ++q) {
        float4 a = *(const float4*)&A_log[d * D_STATE + q * 4];
        A2[q*4+0] = -expf(a.x) * LOG2E;
        A2[q*4+1] = -expf(a.y) * LOG2E;
        A2[q*4+2] = -expf(a.z) * LOG2E;
        A2[q*4+3] = -expf(a.w) * LOG2E;
    }
    float Dv = Dp[d];

    float h[16];
    size_t cb = (((size_t)chunk * 2 + b) * D_INNER + d) * D_STATE;
#pragma unroll
    for (int q = 0; q < 4; ++q) {
        float4 hh = *(const float4*)&carry_h[cb + q * 4];
        h[q*4+0] = hh.x; h[q*4+1] = hh.y; h[q*4+2] = hh.z; h[q*4+3] = hh.w;
    }

    const float* dp = delta + (size_t)rb0 * D_INNER + d;
    const float* up = uc    + (size_t)rb0 * D_INNER + d;
    const float* zp = xz    + (size_t)rb0 * (2 * D_INNER) + D_INNER + d;
    short* yhp = ygh + (size_t)rb0 * D_INNER + d;
    short* ylp = ygl + (size_t)rb0 * D_INNER + d;

    float dv = dp[0], uv = up[0], zv = zp[0];
    for (int l = 0; l < SCL; ++l) {
        float dvn = 0.f, uvn = 0.f, zvn = 0.f;
        if (l + 1 < SCL) {
            dvn = dp[(l+1) * D_INNER];
            uvn = up[(l+1) * D_INNER];
            zvn = zp[(size_t)(l+1) * (2 * D_INNER)];
        }
        float du = dv * uv;
        float y = 0.f;
#pragma unroll
        for (int q = 0; q < 4; ++q) {
            float4 bq = *(const float4*)&Bs[l][q * 4];
            float4 cq = *(const float4*)&Cs[l][q * 4];
            h[q*4+0] = fmaf(exp2f(dv * A2[q*4+0]), h[q*4+0], du * bq.x);
            h[q*4+1] = fmaf(exp2f(dv * A2[q*4+1]), h[q*4+1], du * bq.y);
            h[q*4+2] = fmaf(exp2f(dv * A2[q*4+2]), h[q*4+2], du * bq.z);
            h[q*4+3] = fmaf(exp2f(dv * A2[q*4+3]), h[q*4+3], du * bq.w);
            y = fmaf(h[q*4+0], cq.x, y);
            y = fmaf(h[q*4+1], cq.y, y);
            y = fmaf(h[q*4+2], cq.z, y);
            y = fmaf(h[q*4+3], cq.w, y);
        }
        float yd  = fmaf(uv, Dv, y);
        float val = yd * (zv / (1.f + expf(-zv)));
        short hh, ll;
        split_hi_lo(val, hh, ll);
        yhp[l * D_INNER] = hh;
        ylp[l * D_INNER] = ll;
        dv = dvn; uv = uvn; zv = zvn;
    }
}

// ---------------------------------------------------------------- serial scan (ws fallback)
__global__ __launch_bounds__(256) void scan_kernel(const float* __restrict__ delta,
                                                   const float* __restrict__ uc,
                                                   const float* __restrict__ dbc,
                                                   const float* __restrict__ xz,
                                                   const float* __restrict__ A_log,
                                                   const float* __restrict__ Dp,
                                                   short* __restrict__ ygh,
                                                   short* __restrict__ ygl)
{
    int tid = threadIdx.x;
    int g = tid >> 4, n = tid & 15;
    int bid = blockIdx.x;
    int b = bid >> 7;
    int d = (bid & 127) * 16 + g;
    float Adn = -expf(A_log[d * D_STATE + n]);
    float Dv  = Dp[d];
    float h = 0.f;
    size_t rowb = (size_t)b * LSEQ;

    float dv = delta[rowb * D_INNER + d];
    float uv = uc[rowb * D_INNER + d];
    float Bv = dbc[rowb * 96 + DT_RANK + n];
    float Cv = dbc[rowb * 96 + DT_RANK + D_STATE + n];

    for (int l = 0; l < LSEQ; ++l) {
        float dv_n = 0.f, uv_n = 0.f, Bv_n = 0.f, Cv_n = 0.f;
        if (l + 1 < LSEQ) {
            size_t r = rowb + l + 1;
            dv_n = delta[r * D_INNER + d];
            uv_n = uc[r * D_INNER + d];
            Bv_n = dbc[r * 96 + DT_RANK + n];
            Cv_n = dbc[r * 96 + DT_RANK + D_STATE + n];
        }
        float dA = expf(dv * Adn);
        h = fmaf(dA, h, dv * uv * Bv);
        float p = h * Cv;
        p += __shfl_xor(p, 1);
        p += __shfl_xor(p, 2);
        p += __shfl_xor(p, 4);
        p += __shfl_xor(p, 8);
        if (n == 0) {
            size_t r = rowb + l;
            float zv = xz[r * (2 * D_INNER) + D_INNER + d];
            float y  = fmaf(uv, Dv, p);
            float val = y * (zv / (1.f + expf(-zv)));
            short hh, ll;
            split_hi_lo(val, hh, ll);
            ygh[r * D_INNER + d] = hh;
            ygl[r * D_INNER + d] = ll;
        }
        dv = dv_n; uv = uv_n; Bv = Bv_n; Cv = Cv_n;
    }
}

// ---------------------------------------------------------------- launch
extern "C" void kernel_launch(void* const* d_in, const int* in_sizes, int n_in,
                              void* d_out, int out_size, void* d_ws, size_t ws_size,
                              hipStream_t stream)
{
    const float* x      = (const float*)d_in[0];
    const float* ln_w   = (const float*)d_in[1];
    const float* ln_b   = (const float*)d_in[2];
    const float* W_in   = (const float*)d_in[3];
    const float* conv_w = (const float*)d_in[4];
    const float* conv_b = (const float*)d_in[5];
    const float* W_xprj = (const float*)d_in[6];
    const float* W_dt   = (const float*)d_in[7];
    const float* b_dt   = (const float*)d_in[8];
    const float* A_log  = (const float*)d_in[9];
    const float* Dp     = (const float*)d_in[10];
    const float* W_out  = (const float*)d_in[11];
    float* out = (float*)d_out;

    // fp32 segments: 135,790,592 B
    float* xz    = (float*)d_ws;                          // 4096*4096
    float* uc    = xz    + (size_t)NTOK * 2 * D_INNER;    // 4096*2048
    float* dbc   = uc    + (size_t)NTOK * D_INNER;        // 4096*96
    float* delta = dbc   + (size_t)NTOK * 96;             // 4096*2048
    // bf16 (short) region: 20 Mi shorts, phase-reused
    short* s0    = (short*)(delta + (size_t)NTOK * D_INNER);
    short* nh    = s0;                                    // phase A
    short* nl    = nh   + (size_t)NTOK * D_MODEL;
    short* wiTh  = nl   + (size_t)NTOK * D_MODEL;
    short* wiTl  = wiTh + (size_t)(2 * D_INNER) * D_MODEL;
    short* ygh   = s0;                                    // phase B (aliases A)
    short* ygl   = ygh  + (size_t)NTOK * D_INNER;
    short* woTh  = ygl  + (size_t)NTOK * D_INNER;
    short* woTl  = woTh + (size_t)D_MODEL * D_INNER;
    // xproj partials: XKS x 4096 x 96 fp32 = 6.3 MB, alias dead phase-A region
    float* xpart = (float*)s0;
    // scan carries: 2 x 8 MiB after the bf16 region
    float* carry_A = (float*)(s0 + (size_t)20971520);
    float* carry_h = carry_A + (size_t)2 * D_INNER * D_STATE * SCH;

    size_t needed_base = (size_t)135790592 + (size_t)41943040;
    size_t needed_fast = needed_base + (size_t)2 * 2 * D_INNER * D_STATE * SCH * 4;
    if (ws_size < needed_base) return;
    bool fast_scan = (ws_size >= needed_fast);

    // 0. weight transpose+split
    cvtT_k<<<dim3(2 * D_INNER / 64, D_MODEL / 64), 256, 0, stream>>>(W_in, wiTh, wiTl, D_MODEL, 2 * D_INNER);
    cvtT_k<<<dim3(D_MODEL / 64, D_INNER / 64), 256, 0, stream>>>(W_out, woTh, woTl, D_INNER, D_MODEL);
    // 1. LayerNorm -> bf16 hi/lo
    ln_kernel<<<NTOK, 256, 0, stream>>>(x, ln_w, ln_b, nh, nl);
    // 2. xz = normed @ W_in   (bf16x3 MFMA)
    mgemm_k<0><<<dim3(2 * D_INNER / 128, NTOK / 128), 256, 0, stream>>>(
        nh, nl, wiTh, wiTl, xz, 2 * D_INNER, D_MODEL, nullptr);
    // 3. depthwise conv + SiLU
    conv_silu_kernel<<<(NTOK * D_INNER) / 256, 256, 0, stream>>>(xz, conv_w, conv_b, uc);
    // 4. dbc = uc @ W_xproj   (split-K skinny GEMM; phase-A bf16 region is dead now)
    xproj_k<<<dim3(NTOK / 256, 12, XKS), 256, 0, stream>>>(uc, W_xprj, xpart);
    xreduce_k<<<(NTOK * 96 / 4) / 256, 256, 0, stream>>>(xpart, dbc);
    // 5. delta = softplus(dt @ W_dt + b_dt)
    sgemm128_k<1><<<dim3(D_INNER / TBN, NTOK / TBM), 256, 0, stream>>>(
        dbc, 96, W_dt, D_INNER, delta, D_INNER, DT_RANK, b_dt);
    // 6. selective scan + gating -> bf16 hi/lo
    if (fast_scan) {
        scan1_kernel<<<dim3(SCH, D_INNER / 256, 2), 256, 0, stream>>>(
            delta, uc, dbc, A_log, carry_A, carry_h);
        scan2_kernel<<<(2 * D_INNER * D_STATE) / 256, 256, 0, stream>>>(carry_A, carry_h);
        scan3_kernel<<<dim3(SCH, D_INNER / 256, 2), 256, 0, stream>>>(
            delta, uc, dbc, xz, A_log, Dp, carry_h, ygh, ygl);
    } else {
        scan_kernel<<<256, 256, 0, stream>>>(delta, uc, dbc, xz, A_log, Dp, ygh, ygl);
    }
    // 7. out = x + yg @ W_out  (bf16x3 MFMA)
    mgemm_k<2><<<dim3(D_MODEL / 128, NTOK / 128), 256, 0, stream>>>(
        ygh, ygl, woTh, woTl, out, D_MODEL, D_INNER, x);
}

// Round 10
// 569.251 us; speedup vs baseline: 3.1485x; 1.0523x over previous
//
#include <hip/hip_runtime.h>
#include <math.h>

#define D_MODEL 1024
#define D_INNER 2048
#define D_STATE 16
#define DT_RANK 64
#define LSEQ    2048
#define NTOK    4096   // B * L
#define SCH     32     // scan chunks
#define SCL     (LSEQ / SCH)   // 64 steps per chunk
#define LOG2E   1.44269504088896f
#define XKS     4      // xproj K-splits
#define XKC     (D_INNER / XKS)

typedef short bf16x8 __attribute__((ext_vector_type(8)));
typedef float f32x4  __attribute__((ext_vector_type(4)));

__device__ __forceinline__ unsigned bf16_rne(float v) {
    unsigned u = __float_as_uint(v);
    return (u + 0x7FFFu + ((u >> 16) & 1u)) >> 16;
}
__device__ __forceinline__ void split_hi_lo(float v, short& h, short& l) {
    unsigned hb = bf16_rne(v);
    h = (short)hb;
    float r = v - __uint_as_float(hb << 16);
    l = (short)bf16_rne(r);
}

// ---------------------------------------------------------------- LayerNorm -> bf16 hi/lo
__global__ __launch_bounds__(256) void ln_kernel(const float* __restrict__ x,
                                                 const float* __restrict__ w,
                                                 const float* __restrict__ b,
                                                 short* __restrict__ nh,
                                                 short* __restrict__ nl)
{
    int t = blockIdx.x;
    const float4* xr = (const float4*)(x + (size_t)t * D_MODEL);
    float4 v = xr[threadIdx.x];
    float s  = v.x + v.y + v.z + v.w;
    float s2 = v.x*v.x + v.y*v.y + v.z*v.z + v.w*v.w;
    for (int off = 32; off > 0; off >>= 1) {
        s  += __shfl_down(s, off);
        s2 += __shfl_down(s2, off);
    }
    __shared__ float red[8];
    int wid = threadIdx.x >> 6, lane = threadIdx.x & 63;
    if (lane == 0) { red[wid] = s; red[4 + wid] = s2; }
    __syncthreads();
    if (threadIdx.x == 0) {
        float a = red[0] + red[1] + red[2] + red[3];
        float c = red[4] + red[5] + red[6] + red[7];
        red[0] = a * (1.f / (float)D_MODEL);
        red[4] = c * (1.f / (float)D_MODEL);
    }
    __syncthreads();
    float mu  = red[0];
    float var = red[4] - mu * mu;
    float rs  = rsqrtf(var + 1e-5f);
    float4 wv = ((const float4*)w)[threadIdx.x];
    float4 bv = ((const float4*)b)[threadIdx.x];
    float4 o;
    o.x = (v.x - mu) * rs * wv.x + bv.x;
    o.y = (v.y - mu) * rs * wv.y + bv.y;
    o.z = (v.z - mu) * rs * wv.z + bv.z;
    o.w = (v.w - mu) * rs * wv.w + bv.w;
    short4 h4, l4;
    split_hi_lo(o.x, h4.x, l4.x);
    split_hi_lo(o.y, h4.y, l4.y);
    split_hi_lo(o.z, h4.z, l4.z);
    split_hi_lo(o.w, h4.w, l4.w);
    size_t off = (size_t)t * D_MODEL + threadIdx.x * 4;
    *(short4*)&nh[off] = h4;
    *(short4*)&nl[off] = l4;
}

// -------------------------------------------- transpose + split fp32 W[R][C] -> [C][R] bf16 hi/lo
__global__ __launch_bounds__(256) void cvtT_k(const float* __restrict__ W,
                                              short* __restrict__ Th,
                                              short* __restrict__ Tl,
                                              int R, int Cc)
{
    __shared__ float t[64][65];
    int rr = threadIdx.x >> 4;
    int cc = (threadIdx.x & 15) << 2;
    int r0 = blockIdx.y * 64, c0 = blockIdx.x * 64;
#pragma unroll
    for (int s = 0; s < 4; ++s) {
        float4 v = *(const float4*)&W[(size_t)(r0 + rr + 16*s) * Cc + c0 + cc];
        t[rr+16*s][cc+0] = v.x; t[rr+16*s][cc+1] = v.y;
        t[rr+16*s][cc+2] = v.z; t[rr+16*s][cc+3] = v.w;
    }
    __syncthreads();
#pragma unroll
    for (int s = 0; s < 4; ++s) {
        int orow = rr + 16*s;
        short4 h4, l4;
        split_hi_lo(t[cc+0][orow], h4.x, l4.x);
        split_hi_lo(t[cc+1][orow], h4.y, l4.y);
        split_hi_lo(t[cc+2][orow], h4.z, l4.z);
        split_hi_lo(t[cc+3][orow], h4.w, l4.w);
        size_t off = (size_t)(c0 + orow) * R + r0 + cc;
        *(short4*)&Th[off] = h4;
        *(short4*)&Tl[off] = l4;
    }
}

// ---------------------------------------------------------------- bf16x3 MFMA GEMM
// Fragment-major LDS, double-buffered 2-phase prefetch:
//   STAGE(buf^1, next) ; ds_read(buf) ; 48 MFMA ; barrier ; buf^=1
// so global->LDS latency hides under the compute phase (one barrier/K-step).
template<int EPI>
__global__ __launch_bounds__(256) void mgemm_k(const short* __restrict__ Ah,
                                               const short* __restrict__ Al,
                                               const short* __restrict__ Bh,
                                               const short* __restrict__ Bl,
                                               float* __restrict__ C, int ldc,
                                               int K, const float* __restrict__ aux)
{
    __shared__ short lds[2][4][128 * 32];   // [buf][Ah|Al|Bh|Bl]

    int tid  = threadIdx.x;
    int w    = tid >> 6;
    int lane = tid & 63;
    int wr   = w >> 1, wc = w & 1;
    int row0 = blockIdx.y * 128;
    int col0 = blockIdx.x * 128;

    const short* gA = (w & 1) ? Al : Ah;
    const short* gB = (w & 1) ? Bl : Bh;
    const short* g  = (w & 2) ? gB : gA;
    int obase       = (w & 2) ? col0 : row0;
    const short* gtile = g + (size_t)obase * K;

    int fr = lane & 15;
    int kg = lane >> 4;

    f32x4 acc[4][4] = {};

#if __has_builtin(__builtin_amdgcn_global_load_lds)
#define STAGE(bufi, kk)                                                          \
    {                                                                            \
        _Pragma("unroll")                                                        \
        for (int i = 0; i < 8; ++i) {                                            \
            const short* src = gtile + (size_t)(i * 16 + fr) * K + (kk) + kg * 8;\
            __builtin_amdgcn_global_load_lds(                                    \
                (const __attribute__((address_space(1))) void*)src,              \
                (__attribute__((address_space(3))) void*)&lds[bufi][w][i * 512], \
                16, 0, 0);                                                       \
        }                                                                        \
    }

    STAGE(0, 0);
    __syncthreads();          // drain prologue loads
    int buf = 0;
    for (int k0 = 0; k0 < K; k0 += 32) {
        if (k0 + 32 < K) STAGE(buf ^ 1, k0 + 32);   // prefetch flies under compute

        bf16x8 a_h[4], a_l[4], b_h[4], b_l[4];
#pragma unroll
        for (int m = 0; m < 4; ++m) {
            int ra = ((wr * 4 + m) * 4 + kg) * 128 + fr * 8;
            int rb = ((wc * 4 + m) * 4 + kg) * 128 + fr * 8;
            a_h[m] = *(const bf16x8*)&lds[buf][0][ra];
            a_l[m] = *(const bf16x8*)&lds[buf][1][ra];
            b_h[m] = *(const bf16x8*)&lds[buf][2][rb];
            b_l[m] = *(const bf16x8*)&lds[buf][3][rb];
        }
#pragma unroll
        for (int m = 0; m < 4; ++m)
#pragma unroll
            for (int n = 0; n < 4; ++n)
                acc[m][n] = __builtin_amdgcn_mfma_f32_16x16x32_bf16(a_h[m], b_h[n], acc[m][n], 0, 0, 0);
#pragma unroll
        for (int m = 0; m < 4; ++m)
#pragma unroll
            for (int n = 0; n < 4; ++n)
                acc[m][n] = __builtin_amdgcn_mfma_f32_16x16x32_bf16(a_l[m], b_h[n], acc[m][n], 0, 0, 0);
#pragma unroll
        for (int m = 0; m < 4; ++m)
#pragma unroll
            for (int n = 0; n < 4; ++n)
                acc[m][n] = __builtin_amdgcn_mfma_f32_16x16x32_bf16(a_h[m], b_l[n], acc[m][n], 0, 0, 0);

        __syncthreads();      // drain prefetch remainder + guard buffer swap
        buf ^= 1;
    }
#undef STAGE
#else
    // reg-staging fallback (2-barrier, single buffer in lds[0..1 flattened])
    int srow  = lane >> 2;
    int skc   = lane & 3;
    int swoff = skc * 128 + srow * 8;
    for (int k0 = 0; k0 < K; k0 += 32) {
        bf16x8 stg[8];
#pragma unroll
        for (int i = 0; i < 8; ++i)
            stg[i] = *(const bf16x8*)(gtile + (size_t)(i * 16 + srow) * K + k0 + skc * 8);
        __syncthreads();
#pragma unroll
        for (int i = 0; i < 8; ++i)
            *(bf16x8*)&lds[0][w][i * 512 + swoff] = stg[i];
        __syncthreads();
        bf16x8 a_h[4], a_l[4], b_h[4], b_l[4];
#pragma unroll
        for (int m = 0; m < 4; ++m) {
            int ra = ((wr * 4 + m) * 4 + kg) * 128 + fr * 8;
            int rb = ((wc * 4 + m) * 4 + kg) * 128 + fr * 8;
            a_h[m] = *(const bf16x8*)&lds[0][0][ra];
            a_l[m] = *(const bf16x8*)&lds[0][1][ra];
            b_h[m] = *(const bf16x8*)&lds[0][2][rb];
            b_l[m] = *(const bf16x8*)&lds[0][3][rb];
        }
#pragma unroll
        for (int m = 0; m < 4; ++m)
#pragma unroll
            for (int n = 0; n < 4; ++n) {
                acc[m][n] = __builtin_amdgcn_mfma_f32_16x16x32_bf16(a_h[m], b_h[n], acc[m][n], 0, 0, 0);
                acc[m][n] = __builtin_amdgcn_mfma_f32_16x16x32_bf16(a_l[m], b_h[n], acc[m][n], 0, 0, 0);
                acc[m][n] = __builtin_amdgcn_mfma_f32_16x16x32_bf16(a_h[m], b_l[n], acc[m][n], 0, 0, 0);
            }
    }
#endif

    // C/D layout (m89-verified): col = lane&15, row = (lane>>4)*4 + reg
#pragma unroll
    for (int m = 0; m < 4; ++m) {
        int row = row0 + wr * 64 + m * 16 + kg * 4;
#pragma unroll
        for (int n = 0; n < 4; ++n) {
            int col = col0 + wc * 64 + n * 16 + fr;
#pragma unroll
            for (int j = 0; j < 4; ++j) {
                size_t off = (size_t)(row + j) * ldc + col;
                float v = acc[m][n][j];
                if (EPI == 2) v += aux[off];
                C[off] = v;
            }
        }
    }
}

// ---------------------------------------------------------------- SGEMM 128x128 fp32 (dt-proj)
#define TBM 128
#define TBN 128
#define TBK 16

template<int EPI>
__global__ __launch_bounds__(256) void sgemm128_k(const float* __restrict__ A, int lda,
                                                  const float* __restrict__ B, int ldb,
                                                  float* __restrict__ C, int ldc,
                                                  int K, const float* __restrict__ aux)
{
    __shared__ float As[TBK][TBM + 4];
    __shared__ float Bs[TBK][TBN + 4];

    int tid  = threadIdx.x;
    int row0 = blockIdx.y * TBM;
    int col0 = blockIdx.x * TBN;

    int arow = tid >> 2;
    int acol = (tid & 3) << 2;
    int brow = tid >> 5;
    int bcol = (tid & 31) << 2;

    int tr = tid >> 4;
    int tc = tid & 15;

    float acc[8][8] = {};

    for (int k0 = 0; k0 < K; k0 += TBK) {
        float4 a0 = *(const float4*)(A + (size_t)(row0 + arow)      * lda + k0 + acol);
        float4 a1 = *(const float4*)(A + (size_t)(row0 + arow + 64) * lda + k0 + acol);
        float4 b0 = *(const float4*)(B + (size_t)(k0 + brow)     * ldb + col0 + bcol);
        float4 b1 = *(const float4*)(B + (size_t)(k0 + brow + 8) * ldb + col0 + bcol);
        __syncthreads();
        As[acol + 0][arow] = a0.x;
        As[acol + 1][arow] = a0.y;
        As[acol + 2][arow] = a0.z;
        As[acol + 3][arow] = a0.w;
        As[acol + 0][arow + 64] = a1.x;
        As[acol + 1][arow + 64] = a1.y;
        As[acol + 2][arow + 64] = a1.z;
        As[acol + 3][arow + 64] = a1.w;
        *(float4*)&Bs[brow][bcol]     = b0;
        *(float4*)&Bs[brow + 8][bcol] = b1;
        __syncthreads();
#pragma unroll
        for (int kk = 0; kk < TBK; ++kk) {
            float4 x0 = *(const float4*)&As[kk][tr << 2];
            float4 x1 = *(const float4*)&As[kk][(tr << 2) + 64];
            float4 y0 = *(const float4*)&Bs[kk][tc << 2];
            float4 y1 = *(const float4*)&Bs[kk][(tc << 2) + 64];
            float xa[8] = {x0.x, x0.y, x0.z, x0.w, x1.x, x1.y, x1.z, x1.w};
            float yb[8] = {y0.x, y0.y, y0.z, y0.w, y1.x, y1.y, y1.z, y1.w};
#pragma unroll
            for (int i = 0; i < 8; ++i)
#pragma unroll
                for (int j = 0; j < 8; ++j)
                    acc[i][j] = fmaf(xa[i], yb[j], acc[i][j]);
        }
    }

#pragma unroll
    for (int ih = 0; ih < 2; ++ih) {
#pragma unroll
        for (int i = 0; i < 4; ++i) {
            int r = row0 + (tr << 2) + ih * 64 + i;
#pragma unroll
            for (int jh = 0; jh < 2; ++jh) {
                int c = col0 + (tc << 2) + jh * 64;
                size_t off = (size_t)r * ldc + c;
                float4 v = *(const float4*)&acc[ih * 4 + i][jh * 4];
                if (EPI == 1) {
                    float4 bb = *(const float4*)(aux + c);
                    float t0;
                    t0 = v.x + bb.x; v.x = fmaxf(t0, 0.f) + log1pf(expf(-fabsf(t0)));
                    t0 = v.y + bb.y; v.y = fmaxf(t0, 0.f) + log1pf(expf(-fabsf(t0)));
                    t0 = v.z + bb.z; v.z = fmaxf(t0, 0.f) + log1pf(expf(-fabsf(t0)));
                    t0 = v.w + bb.w; v.w = fmaxf(t0, 0.f) + log1pf(expf(-fabsf(t0)));
                } else if (EPI == 2) {
                    float4 rr = *(const float4*)(aux + off);
                    v.x += rr.x; v.y += rr.y; v.z += rr.z; v.w += rr.w;
                }
                *(float4*)(C + off) = v;
            }
        }
    }
}

// ---------------------------------------------------------------- xproj skinny GEMM, split-K
__global__ __launch_bounds__(256) void xproj_k(const float* __restrict__ A,
                                               const float* __restrict__ W,
                                               float* __restrict__ part)
{
    int row = blockIdx.x * 256 + threadIdx.x;
    int cg  = blockIdx.y;
    int ks  = blockIdx.z;
    const float4* a4 = (const float4*)(A + (size_t)row * D_INNER + ks * XKC);
    const float* w = W + (size_t)ks * XKC * 96 + cg * 8;
    float acc[8] = {};
#pragma unroll 2
    for (int k4 = 0; k4 < XKC / 4; ++k4) {
        float4 av = a4[k4];
        const float* wk = w + (size_t)k4 * 4 * 96;
        float a0 = av.x, a1 = av.y, a2 = av.z, a3 = av.w;
#pragma unroll
        for (int kk = 0; kk < 4; ++kk) {
            float ak = (kk == 0) ? a0 : (kk == 1) ? a1 : (kk == 2) ? a2 : a3;
            float4 w0 = *(const float4*)(wk + (size_t)kk * 96);
            float4 w1 = *(const float4*)(wk + (size_t)kk * 96 + 4);
            acc[0] = fmaf(ak, w0.x, acc[0]);
            acc[1] = fmaf(ak, w0.y, acc[1]);
            acc[2] = fmaf(ak, w0.z, acc[2]);
            acc[3] = fmaf(ak, w0.w, acc[3]);
            acc[4] = fmaf(ak, w1.x, acc[4]);
            acc[5] = fmaf(ak, w1.y, acc[5]);
            acc[6] = fmaf(ak, w1.z, acc[6]);
            acc[7] = fmaf(ak, w1.w, acc[7]);
        }
    }
    float* p = part + ((size_t)ks * NTOK + row) * 96 + cg * 8;
    *(float4*)p       = *(float4*)&acc[0];
    *(float4*)(p + 4) = *(float4*)&acc[4];
}

__global__ __launch_bounds__(256) void xreduce_k(const float* __restrict__ part,
                                                 float* __restrict__ dbc)
{
    int i = blockIdx.x * 256 + threadIdx.x;
    const float4* p = (const float4*)part;
    float4 s0 = p[i];
    float4 s1 = p[i + 98304];
    float4 s2 = p[i + 2 * 98304];
    float4 s3 = p[i + 3 * 98304];
    float4 s;
    s.x = (s0.x + s1.x) + (s2.x + s3.x);
    s.y = (s0.y + s1.y) + (s2.y + s3.y);
    s.z = (s0.z + s1.z) + (s2.z + s3.z);
    s.w = (s0.w + s1.w) + (s2.w + s3.w);
    ((float4*)dbc)[i] = s;
}

// ------------------------------------------------- depthwise causal conv + SiLU
__global__ __launch_bounds__(256) void conv_silu_kernel(const float* __restrict__ xz,
                                                        const float* __restrict__ conv_w,
                                                        const float* __restrict__ conv_b,
                                                        float* __restrict__ uc)
{
    int idx = blockIdx.x * 256 + threadIdx.x;
    if (idx >= NTOK * D_INNER) return;
    int d  = idx & (D_INNER - 1);
    int bl = idx >> 11;
    int l  = bl & (LSEQ - 1);
    float4 w = ((const float4*)conv_w)[d];
    float acc = conv_b[d];
    if (l >= 3) acc += w.x * xz[(size_t)(bl - 3) * (2 * D_INNER) + d];
    if (l >= 2) acc += w.y * xz[(size_t)(bl - 2) * (2 * D_INNER) + d];
    if (l >= 1) acc += w.z * xz[(size_t)(bl - 1) * (2 * D_INNER) + d];
    acc += w.w * xz[(size_t)bl * (2 * D_INNER) + d];
    uc[idx] = acc / (1.f + expf(-acc));
}

// ---------------------------------------------------------------- chunked scan (thread-per-channel)
__global__ __launch_bounds__(256) void scan1_kernel(const float* __restrict__ delta,
                                                    const float* __restrict__ uc,
                                                    const float* __restrict__ dbc,
                                                    const float* __restrict__ A_log,
                                                    float* __restrict__ carry_A,
                                                    float* __restrict__ carry_h)
{
    __shared__ float Bs[SCL][16];
    int tid = threadIdx.x;
    int chunk = blockIdx.x, dg = blockIdx.y, b = blockIdx.z;
    int d = dg * 256 + tid;
    int rb0 = b * LSEQ + chunk * SCL;

    for (int i = tid; i < SCL * 16; i += 256) {
        int l = i >> 4, n = i & 15;
        Bs[l][n] = dbc[(size_t)(rb0 + l) * 96 + DT_RANK + n];
    }
    __syncthreads();

    float A2[16];
#pragma unroll
    for (int q = 0; q < 4; ++q) {
        float4 a = *(const float4*)&A_log[d * D_STATE + q * 4];
        A2[q*4+0] = -expf(a.x) * LOG2E;
        A2[q*4+1] = -expf(a.y) * LOG2E;
        A2[q*4+2] = -expf(a.z) * LOG2E;
        A2[q*4+3] = -expf(a.w) * LOG2E;
    }

    float h[16];
#pragma unroll
    for (int n = 0; n < 16; ++n) h[n] = 0.f;
    float sdv = 0.f;

    const float* dp = delta + (size_t)rb0 * D_INNER + d;
    const float* up = uc    + (size_t)rb0 * D_INNER + d;

    float dv = dp[0], uv = up[0];
    for (int l = 0; l < SCL; ++l) {
        float dvn = 0.f, uvn = 0.f;
        if (l + 1 < SCL) { dvn = dp[(l+1) * D_INNER]; uvn = up[(l+1) * D_INNER]; }
        float du = dv * uv;
        sdv += dv;
#pragma unroll
        for (int q = 0; q < 4; ++q) {
            float4 bq = *(const float4*)&Bs[l][q * 4];
            h[q*4+0] = fmaf(exp2f(dv * A2[q*4+0]), h[q*4+0], du * bq.x);
            h[q*4+1] = fmaf(exp2f(dv * A2[q*4+1]), h[q*4+1], du * bq.y);
            h[q*4+2] = fmaf(exp2f(dv * A2[q*4+2]), h[q*4+2], du * bq.z);
            h[q*4+3] = fmaf(exp2f(dv * A2[q*4+3]), h[q*4+3], du * bq.w);
        }
        dv = dvn; uv = uvn;
    }

    size_t cb = (((size_t)chunk * 2 + b) * D_INNER + d) * D_STATE;
#pragma unroll
    for (int q = 0; q < 4; ++q) {
        float4 ap, hh;
        ap.x = exp2f(sdv * A2[q*4+0]); ap.y = exp2f(sdv * A2[q*4+1]);
        ap.z = exp2f(sdv * A2[q*4+2]); ap.w = exp2f(sdv * A2[q*4+3]);
        hh.x = h[q*4+0]; hh.y = h[q*4+1]; hh.z = h[q*4+2]; hh.w = h[q*4+3];
        *(float4*)&carry_A[cb + q * 4] = ap;
        *(float4*)&carry_h[cb + q * 4] = hh;
    }
}

__global__ __launch_bounds__(256) void scan2_kernel(const float* __restrict__ carry_A,
                                                    float* __restrict__ carry_h)
{
    int idx = blockIdx.x * 256 + threadIdx.x;
    float h = 0.f;
#pragma unroll
    for (int c = 0; c < SCH; ++c) {
        size_t a = (size_t)c * (2 * D_INNER * D_STATE) + idx;
        float Ap = carry_A[a];
        float he = carry_h[a];
        carry_h[a] = h;
        h = fmaf(Ap, h, he);
    }
}

__global__ __launch_bounds__(256) void scan3_kernel(const float* __restrict__ delta,
                                                    const float* __restrict__ uc,
                                                    const float* __restrict__ dbc,
                                                    const float* __restrict__ xz,
                                                    const float* __restrict__ A_log,
                                                    const float* __restrict__ Dp,
                                                    const float* __restrict__ carry_h,
                                                    short* __restrict__ ygh,
                                                    short* __restrict__ ygl)
{
    __shared__ float Bs[SCL][16];
    __shared__ float Cs[SCL][16];
    int tid = threadIdx.x;
    int chunk = blockIdx.x, dg = blockIdx.y, b = blockIdx.z;
    int d = dg * 256 + tid;
    int rb0 = b * LSEQ + chunk * SCL;

    for (int i = tid; i < SCL * 32; i += 256) {
        int l = i >> 5, o = i & 31;
        float v = dbc[(size_t)(rb0 + l) * 96 + DT_RANK + o];
        if (o < 16) Bs[l][o] = v; else Cs[l][o - 16] = v;
    }
    __syncthreads();

    float A2[16];
#pragma unroll
    for (int q = 0; q < 4; ++q) {
        float4 a = *(const float4*)&A_log[d * D_STATE + q * 4];
        A2[q*4+0] = -expf(a.x) * LOG2E;
        A2[q*4+1] = -expf(a.y) * LOG2E;
        A2[q*4+2] = -expf(a.z) * LOG2E;
        A2[q*4+3] = -expf(a.w) * LOG2E;
    }
    float Dv = Dp[d];

    float h[16];
    size_t cb = (((size_t)chunk * 2 + b) * D_INNER + d) * D_STATE;
#pragma unroll
    for (int q = 0; q < 4; ++q) {
        float4 hh = *(const float4*)&carry_h[cb + q * 4];
        h[q*4+0] = hh.x; h[q*4+1] = hh.y; h[q*4+2] = hh.z; h[q*4+3] = hh.w;
    }

    const float* dp = delta + (size_t)rb0 * D_INNER + d;
    const float* up = uc    + (size_t)rb0 * D_INNER + d;
    const float* zp = xz    + (size_t)rb0 * (2 * D_INNER) + D_INNER + d;
    short* yhp = ygh + (size_t)rb0 * D_INNER + d;
    short* ylp = ygl + (size_t)rb0 * D_INNER + d;

    float dv = dp[0], uv = up[0], zv = zp[0];
    for (int l = 0; l < SCL; ++l) {
        float dvn = 0.f, uvn = 0.f, zvn = 0.f;
        if (l + 1 < SCL) {
            dvn = dp[(l+1) * D_INNER];
            uvn = up[(l+1) * D_INNER];
            zvn = zp[(size_t)(l+1) * (2 * D_INNER)];
        }
        float du = dv * uv;
        float y = 0.f;
#pragma unroll
        for (int q = 0; q < 4; ++q) {
            float4 bq = *(const float4*)&Bs[l][q * 4];
            float4 cq = *(const float4*)&Cs[l][q * 4];
            h[q*4+0] = fmaf(exp2f(dv * A2[q*4+0]), h[q*4+0], du * bq.x);
            h[q*4+1] = fmaf(exp2f(dv * A2[q*4+1]), h[q*4+1], du * bq.y);
            h[q*4+2] = fmaf(exp2f(dv * A2[q*4+2]), h[q*4+2], du * bq.z);
            h[q*4+3] = fmaf(exp2f(dv * A2[q*4+3]), h[q*4+3], du * bq.w);
            y = fmaf(h[q*4+0], cq.x, y);
            y = fmaf(h[q*4+1], cq.y, y);
            y = fmaf(h[q*4+2], cq.z, y);
            y = fmaf(h[q*4+3], cq.w, y);
        }
        float yd  = fmaf(uv, Dv, y);
        float val = yd * (zv / (1.f + expf(-zv)));
        short hh, ll;
        split_hi_lo(val, hh, ll);
        yhp[l * D_INNER] = hh;
        ylp[l * D_INNER] = ll;
        dv = dvn; uv = uvn; zv = zvn;
    }
}

// ---------------------------------------------------------------- serial scan (ws fallback)
__global__ __launch_bounds__(256) void scan_kernel(const float* __restrict__ delta,
                                                   const float* __restrict__ uc,
                                                   const float* __restrict__ dbc,
                                                   const float* __restrict__ xz,
                                                   const float* __restrict__ A_log,
                                                   const float* __restrict__ Dp,
                                                   short* __restrict__ ygh,
                                                   short* __restrict__ ygl)
{
    int tid = threadIdx.x;
    int g = tid >> 4, n = tid & 15;
    int bid = blockIdx.x;
    int b = bid >> 7;
    int d = (bid & 127) * 16 + g;
    float Adn = -expf(A_log[d * D_STATE + n]);
    float Dv  = Dp[d];
    float h = 0.f;
    size_t rowb = (size_t)b * LSEQ;

    float dv = delta[rowb * D_INNER + d];
    float uv = uc[rowb * D_INNER + d];
    float Bv = dbc[rowb * 96 + DT_RANK + n];
    float Cv = dbc[rowb * 96 + DT_RANK + D_STATE + n];

    for (int l = 0; l < LSEQ; ++l) {
        float dv_n = 0.f, uv_n = 0.f, Bv_n = 0.f, Cv_n = 0.f;
        if (l + 1 < LSEQ) {
            size_t r = rowb + l + 1;
            dv_n = delta[r * D_INNER + d];
            uv_n = uc[r * D_INNER + d];
            Bv_n = dbc[r * 96 + DT_RANK + n];
            Cv_n = dbc[r * 96 + DT_RANK + D_STATE + n];
        }
        float dA = expf(dv * Adn);
        h = fmaf(dA, h, dv * uv * Bv);
        float p = h * Cv;
        p += __shfl_xor(p, 1);
        p += __shfl_xor(p, 2);
        p += __shfl_xor(p, 4);
        p += __shfl_xor(p, 8);
        if (n == 0) {
            size_t r = rowb + l;
            float zv = xz[r * (2 * D_INNER) + D_INNER + d];
            float y  = fmaf(uv, Dv, p);
            float val = y * (zv / (1.f + expf(-zv)));
            short hh, ll;
            split_hi_lo(val, hh, ll);
            ygh[r * D_INNER + d] = hh;
            ygl[r * D_INNER + d] = ll;
        }
        dv = dv_n; uv = uv_n; Bv = Bv_n; Cv = Cv_n;
    }
}

// ---------------------------------------------------------------- launch
extern "C" void kernel_launch(void* const* d_in, const int* in_sizes, int n_in,
                              void* d_out, int out_size, void* d_ws, size_t ws_size,
                              hipStream_t stream)
{
    const float* x      = (const float*)d_in[0];
    const float* ln_w   = (const float*)d_in[1];
    const float* ln_b   = (const float*)d_in[2];
    const float* W_in   = (const float*)d_in[3];
    const float* conv_w = (const float*)d_in[4];
    const float* conv_b = (const float*)d_in[5];
    const float* W_xprj = (const float*)d_in[6];
    const float* W_dt   = (const float*)d_in[7];
    const float* b_dt   = (const float*)d_in[8];
    const float* A_log  = (const float*)d_in[9];
    const float* Dp     = (const float*)d_in[10];
    const float* W_out  = (const float*)d_in[11];
    float* out = (float*)d_out;

    // fp32 segments: 135,790,592 B
    float* xz    = (float*)d_ws;                          // 4096*4096
    float* uc    = xz    + (size_t)NTOK * 2 * D_INNER;    // 4096*2048
    float* dbc   = uc    + (size_t)NTOK * D_INNER;        // 4096*96
    float* delta = dbc   + (size_t)NTOK * 96;             // 4096*2048
    // bf16 (short) region: 20 Mi shorts, phase-reused
    short* s0    = (short*)(delta + (size_t)NTOK * D_INNER);
    short* nh    = s0;                                    // phase A
    short* nl    = nh   + (size_t)NTOK * D_MODEL;
    short* wiTh  = nl   + (size_t)NTOK * D_MODEL;
    short* wiTl  = wiTh + (size_t)(2 * D_INNER) * D_MODEL;
    short* ygh   = s0;                                    // phase B (aliases A)
    short* ygl   = ygh  + (size_t)NTOK * D_INNER;
    short* woTh  = ygl  + (size_t)NTOK * D_INNER;
    short* woTl  = woTh + (size_t)D_MODEL * D_INNER;
    // xproj partials: XKS x 4096 x 96 fp32 = 6.3 MB, alias dead phase-A region
    float* xpart = (float*)s0;
    // scan carries: 2 x 8 MiB after the bf16 region
    float* carry_A = (float*)(s0 + (size_t)20971520);
    float* carry_h = carry_A + (size_t)2 * D_INNER * D_STATE * SCH;

    size_t needed_base = (size_t)135790592 + (size_t)41943040;
    size_t needed_fast = needed_base + (size_t)2 * 2 * D_INNER * D_STATE * SCH * 4;
    if (ws_size < needed_base) return;
    bool fast_scan = (ws_size >= needed_fast);

    // 0. weight transpose+split
    cvtT_k<<<dim3(2 * D_INNER / 64, D_MODEL / 64), 256, 0, stream>>>(W_in, wiTh, wiTl, D_MODEL, 2 * D_INNER);
    cvtT_k<<<dim3(D_MODEL / 64, D_INNER / 64), 256, 0, stream>>>(W_out, woTh, woTl, D_INNER, D_MODEL);
    // 1. LayerNorm -> bf16 hi/lo
    ln_kernel<<<NTOK, 256, 0, stream>>>(x, ln_w, ln_b, nh, nl);
    // 2. xz = normed @ W_in   (bf16x3 MFMA, 2-phase prefetch)
    mgemm_k<0><<<dim3(2 * D_INNER / 128, NTOK / 128), 256, 0, stream>>>(
        nh, nl, wiTh, wiTl, xz, 2 * D_INNER, D_MODEL, nullptr);
    // 3. depthwise conv + SiLU
    conv_silu_kernel<<<(NTOK * D_INNER) / 256, 256, 0, stream>>>(xz, conv_w, conv_b, uc);
    // 4. dbc = uc @ W_xproj   (split-K skinny GEMM)
    xproj_k<<<dim3(NTOK / 256, 12, XKS), 256, 0, stream>>>(uc, W_xprj, xpart);
    xreduce_k<<<(NTOK * 96 / 4) / 256, 256, 0, stream>>>(xpart, dbc);
    // 5. delta = softplus(dt @ W_dt + b_dt)
    sgemm128_k<1><<<dim3(D_INNER / TBN, NTOK / TBM), 256, 0, stream>>>(
        dbc, 96, W_dt, D_INNER, delta, D_INNER, DT_RANK, b_dt);
    // 6. selective scan + gating -> bf16 hi/lo
    if (fast_scan) {
        scan1_kernel<<<dim3(SCH, D_INNER / 256, 2), 256, 0, stream>>>(
            delta, uc, dbc, A_log, carry_A, carry_h);
        scan2_kernel<<<(2 * D_INNER * D_STATE) / 256, 256, 0, stream>>>(carry_A, carry_h);
        scan3_kernel<<<dim3(SCH, D_INNER / 256, 2), 256, 0, stream>>>(
            delta, uc, dbc, xz, A_log, Dp, carry_h, ygh, ygl);
    } else {
        scan_kernel<<<256, 256, 0, stream>>>(delta, uc, dbc, xz, A_log, Dp, ygh, ygl);
    }
    // 7. out = x + yg @ W_out  (bf16x3 MFMA, 2-phase prefetch)
    mgemm_k<2><<<dim3(D_MODEL / 128, NTOK / 128), 256, 0, stream>>>(
        ygh, ygl, woTh, woTl, out, D_MODEL, D_INNER, x);
}

// Round 12
// 540.768 us; speedup vs baseline: 3.3143x; 1.0527x over previous
//
#include <hip/hip_runtime.h>
#include <math.h>

#define D_MODEL 1024
#define D_INNER 2048
#define D_STATE 16
#define DT_RANK 64
#define LSEQ    2048
#define NTOK    4096   // B * L
#define SCH     32     // scan chunks
#define SCL     (LSEQ / SCH)   // 64 steps per chunk
#define LOG2E   1.44269504088896f
#define XKS     4      // xproj K-splits
#define XKC     (D_INNER / XKS)

typedef short bf16x8 __attribute__((ext_vector_type(8)));
typedef float f32x4  __attribute__((ext_vector_type(4)));

__device__ __forceinline__ unsigned bf16_rne(float v) {
    unsigned u = __float_as_uint(v);
    return (u + 0x7FFFu + ((u >> 16) & 1u)) >> 16;
}
__device__ __forceinline__ void split_hi_lo(float v, short& h, short& l) {
    unsigned hb = bf16_rne(v);
    h = (short)hb;
    float r = v - __uint_as_float(hb << 16);
    l = (short)bf16_rne(r);
}

// ---------------------------------------------------------------- LayerNorm -> bf16 hi/lo
__global__ __launch_bounds__(256) void ln_kernel(const float* __restrict__ x,
                                                 const float* __restrict__ w,
                                                 const float* __restrict__ b,
                                                 short* __restrict__ nh,
                                                 short* __restrict__ nl)
{
    int t = blockIdx.x;
    const float4* xr = (const float4*)(x + (size_t)t * D_MODEL);
    float4 v = xr[threadIdx.x];
    float s  = v.x + v.y + v.z + v.w;
    float s2 = v.x*v.x + v.y*v.y + v.z*v.z + v.w*v.w;
    for (int off = 32; off > 0; off >>= 1) {
        s  += __shfl_down(s, off);
        s2 += __shfl_down(s2, off);
    }
    __shared__ float red[8];
    int wid = threadIdx.x >> 6, lane = threadIdx.x & 63;
    if (lane == 0) { red[wid] = s; red[4 + wid] = s2; }
    __syncthreads();
    if (threadIdx.x == 0) {
        float a = red[0] + red[1] + red[2] + red[3];
        float c = red[4] + red[5] + red[6] + red[7];
        red[0] = a * (1.f / (float)D_MODEL);
        red[4] = c * (1.f / (float)D_MODEL);
    }
    __syncthreads();
    float mu  = red[0];
    float var = red[4] - mu * mu;
    float rs  = rsqrtf(var + 1e-5f);
    float4 wv = ((const float4*)w)[threadIdx.x];
    float4 bv = ((const float4*)b)[threadIdx.x];
    float4 o;
    o.x = (v.x - mu) * rs * wv.x + bv.x;
    o.y = (v.y - mu) * rs * wv.y + bv.y;
    o.z = (v.z - mu) * rs * wv.z + bv.z;
    o.w = (v.w - mu) * rs * wv.w + bv.w;
    short4 h4, l4;
    split_hi_lo(o.x, h4.x, l4.x);
    split_hi_lo(o.y, h4.y, l4.y);
    split_hi_lo(o.z, h4.z, l4.z);
    split_hi_lo(o.w, h4.w, l4.w);
    size_t off = (size_t)t * D_MODEL + threadIdx.x * 4;
    *(short4*)&nh[off] = h4;
    *(short4*)&nl[off] = l4;
}

// -------------------------------------------- transpose + split fp32 W[R][C] -> [C][R] bf16 hi/lo
__global__ __launch_bounds__(256) void cvtT_k(const float* __restrict__ W,
                                              short* __restrict__ Th,
                                              short* __restrict__ Tl,
                                              int R, int Cc)
{
    __shared__ float t[64][65];
    int rr = threadIdx.x >> 4;
    int cc = (threadIdx.x & 15) << 2;
    int r0 = blockIdx.y * 64, c0 = blockIdx.x * 64;
#pragma unroll
    for (int s = 0; s < 4; ++s) {
        float4 v = *(const float4*)&W[(size_t)(r0 + rr + 16*s) * Cc + c0 + cc];
        t[rr+16*s][cc+0] = v.x; t[rr+16*s][cc+1] = v.y;
        t[rr+16*s][cc+2] = v.z; t[rr+16*s][cc+3] = v.w;
    }
    __syncthreads();
#pragma unroll
    for (int s = 0; s < 4; ++s) {
        int orow = rr + 16*s;
        short4 h4, l4;
        split_hi_lo(t[cc+0][orow], h4.x, l4.x);
        split_hi_lo(t[cc+1][orow], h4.y, l4.y);
        split_hi_lo(t[cc+2][orow], h4.z, l4.z);
        split_hi_lo(t[cc+3][orow], h4.w, l4.w);
        size_t off = (size_t)(c0 + orow) * R + r0 + cc;
        *(short4*)&Th[off] = h4;
        *(short4*)&Tl[off] = l4;
    }
}

// ---------------------------------------------------------------- bf16x3 MFMA GEMM
// Fragment-major LDS, double-buffered 2-phase prefetch, T5 setprio around MFMA.
// Supports K-split via gridDim.z: slice kz covers K-cols [kz*Kiter, (kz+1)*Kiter),
// writing C + kz*NTOK*ldc. lda = full K stride of A/B rows.
template<int EPI>
__global__ __launch_bounds__(256) void mgemm_k(const short* __restrict__ Ah,
                                               const short* __restrict__ Al,
                                               const short* __restrict__ Bh,
                                               const short* __restrict__ Bl,
                                               float* __restrict__ C, int ldc,
                                               int Kiter, int lda,
                                               const float* __restrict__ aux)
{
    __shared__ short lds[2][4][128 * 32];   // [buf][Ah|Al|Bh|Bl]

    int tid  = threadIdx.x;
    int w    = tid >> 6;
    int lane = tid & 63;
    int wr   = w >> 1, wc = w & 1;
    int row0 = blockIdx.y * 128;
    int col0 = blockIdx.x * 128;
    int kz   = blockIdx.z;

    const short* gA = (w & 1) ? Al : Ah;
    const short* gB = (w & 1) ? Bl : Bh;
    const short* g  = (w & 2) ? gB : gA;
    int obase       = (w & 2) ? col0 : row0;
    const short* gtile = g + (size_t)obase * lda + (size_t)kz * Kiter;
    C += (size_t)kz * NTOK * ldc;

    int fr = lane & 15;
    int kg = lane >> 4;

    f32x4 acc[4][4] = {};

#if __has_builtin(__builtin_amdgcn_global_load_lds)
#define STAGE(bufi, kk)                                                            \
    {                                                                              \
        _Pragma("unroll")                                                          \
        for (int i = 0; i < 8; ++i) {                                              \
            const short* src = gtile + (size_t)(i * 16 + fr) * lda + (kk) + kg * 8;\
            __builtin_amdgcn_global_load_lds(                                      \
                (const __attribute__((address_space(1))) void*)src,                \
                (__attribute__((address_space(3))) void*)&lds[bufi][w][i * 512],   \
                16, 0, 0);                                                         \
        }                                                                          \
    }

    STAGE(0, 0);
    __syncthreads();          // drain prologue loads
    int buf = 0;
    for (int k0 = 0; k0 < Kiter; k0 += 32) {
        if (k0 + 32 < Kiter) STAGE(buf ^ 1, k0 + 32);   // prefetch flies under compute

        bf16x8 a_h[4], a_l[4], b_h[4], b_l[4];
#pragma unroll
        for (int m = 0; m < 4; ++m) {
            int ra = ((wr * 4 + m) * 4 + kg) * 128 + fr * 8;
            int rb = ((wc * 4 + m) * 4 + kg) * 128 + fr * 8;
            a_h[m] = *(const bf16x8*)&lds[buf][0][ra];
            a_l[m] = *(const bf16x8*)&lds[buf][1][ra];
            b_h[m] = *(const bf16x8*)&lds[buf][2][rb];
            b_l[m] = *(const bf16x8*)&lds[buf][3][rb];
        }
        __builtin_amdgcn_s_setprio(1);
#pragma unroll
        for (int m = 0; m < 4; ++m)
#pragma unroll
            for (int n = 0; n < 4; ++n)
                acc[m][n] = __builtin_amdgcn_mfma_f32_16x16x32_bf16(a_h[m], b_h[n], acc[m][n], 0, 0, 0);
#pragma unroll
        for (int m = 0; m < 4; ++m)
#pragma unroll
            for (int n = 0; n < 4; ++n)
                acc[m][n] = __builtin_amdgcn_mfma_f32_16x16x32_bf16(a_l[m], b_h[n], acc[m][n], 0, 0, 0);
#pragma unroll
        for (int m = 0; m < 4; ++m)
#pragma unroll
            for (int n = 0; n < 4; ++n)
                acc[m][n] = __builtin_amdgcn_mfma_f32_16x16x32_bf16(a_h[m], b_l[n], acc[m][n], 0, 0, 0);
        __builtin_amdgcn_s_setprio(0);

        __syncthreads();      // drain prefetch remainder + guard buffer swap
        buf ^= 1;
    }
#undef STAGE
#else
    // reg-staging fallback (2-barrier, single buffer)
    int srow  = lane >> 2;
    int skc   = lane & 3;
    int swoff = skc * 128 + srow * 8;
    for (int k0 = 0; k0 < Kiter; k0 += 32) {
        bf16x8 stg[8];
#pragma unroll
        for (int i = 0; i < 8; ++i)
            stg[i] = *(const bf16x8*)(gtile + (size_t)(i * 16 + srow) * lda + k0 + skc * 8);
        __syncthreads();
#pragma unroll
        for (int i = 0; i < 8; ++i)
            *(bf16x8*)&lds[0][w][i * 512 + swoff] = stg[i];
        __syncthreads();
        bf16x8 a_h[4], a_l[4], b_h[4], b_l[4];
#pragma unroll
        for (int m = 0; m < 4; ++m) {
            int ra = ((wr * 4 + m) * 4 + kg) * 128 + fr * 8;
            int rb = ((wc * 4 + m) * 4 + kg) * 128 + fr * 8;
            a_h[m] = *(const bf16x8*)&lds[0][0][ra];
            a_l[m] = *(const bf16x8*)&lds[0][1][ra];
            b_h[m] = *(const bf16x8*)&lds[0][2][rb];
            b_l[m] = *(const bf16x8*)&lds[0][3][rb];
        }
#pragma unroll
        for (int m = 0; m < 4; ++m)
#pragma unroll
            for (int n = 0; n < 4; ++n) {
                acc[m][n] = __builtin_amdgcn_mfma_f32_16x16x32_bf16(a_h[m], b_h[n], acc[m][n], 0, 0, 0);
                acc[m][n] = __builtin_amdgcn_mfma_f32_16x16x32_bf16(a_l[m], b_h[n], acc[m][n], 0, 0, 0);
                acc[m][n] = __builtin_amdgcn_mfma_f32_16x16x32_bf16(a_h[m], b_l[n], acc[m][n], 0, 0, 0);
            }
    }
#endif

    // C/D layout (m89-verified): col = lane&15, row = (lane>>4)*4 + reg
#pragma unroll
    for (int m = 0; m < 4; ++m) {
        int row = row0 + wr * 64 + m * 16 + kg * 4;
#pragma unroll
        for (int n = 0; n < 4; ++n) {
            int col = col0 + wc * 64 + n * 16 + fr;
#pragma unroll
            for (int j = 0; j < 4; ++j) {
                size_t off = (size_t)(row + j) * ldc + col;
                float v = acc[m][n][j];
                if (EPI == 2) v += aux[off];
                C[off] = v;
            }
        }
    }
}

// ---------------------------------------------------------------- out = x + p0 + p1 (split-K reduce)
__global__ __launch_bounds__(256) void outred_k(const float* __restrict__ x,
                                                const float* __restrict__ part,
                                                float* __restrict__ out)
{
    int i = blockIdx.x * 256 + threadIdx.x;    // over 4096*1024/4 float4s
    float4 xv = ((const float4*)x)[i];
    float4 p0 = ((const float4*)part)[i];
    float4 p1 = ((const float4*)part)[i + (NTOK * D_MODEL / 4)];
    float4 o;
    o.x = xv.x + p0.x + p1.x;
    o.y = xv.y + p0.y + p1.y;
    o.z = xv.z + p0.z + p1.z;
    o.w = xv.w + p0.w + p1.w;
    ((float4*)out)[i] = o;
}

// ---------------------------------------------------------------- SGEMM 128x128 fp32 (dt-proj)
#define TBM 128
#define TBN 128
#define TBK 16

template<int EPI>
__global__ __launch_bounds__(256) void sgemm128_k(const float* __restrict__ A, int lda,
                                                  const float* __restrict__ B, int ldb,
                                                  float* __restrict__ C, int ldc,
                                                  int K, const float* __restrict__ aux)
{
    __shared__ float As[TBK][TBM + 4];
    __shared__ float Bs[TBK][TBN + 4];

    int tid  = threadIdx.x;
    int row0 = blockIdx.y * TBM;
    int col0 = blockIdx.x * TBN;

    int arow = tid >> 2;
    int acol = (tid & 3) << 2;
    int brow = tid >> 5;
    int bcol = (tid & 31) << 2;

    int tr = tid >> 4;
    int tc = tid & 15;

    float acc[8][8] = {};

    for (int k0 = 0; k0 < K; k0 += TBK) {
        float4 a0 = *(const float4*)(A + (size_t)(row0 + arow)      * lda + k0 + acol);
        float4 a1 = *(const float4*)(A + (size_t)(row0 + arow + 64) * lda + k0 + acol);
        float4 b0 = *(const float4*)(B + (size_t)(k0 + brow)     * ldb + col0 + bcol);
        float4 b1 = *(const float4*)(B + (size_t)(k0 + brow + 8) * ldb + col0 + bcol);
        __syncthreads();
        As[acol + 0][arow] = a0.x;
        As[acol + 1][arow] = a0.y;
        As[acol + 2][arow] = a0.z;
        As[acol + 3][arow] = a0.w;
        As[acol + 0][arow + 64] = a1.x;
        As[acol + 1][arow + 64] = a1.y;
        As[acol + 2][arow + 64] = a1.z;
        As[acol + 3][arow + 64] = a1.w;
        *(float4*)&Bs[brow][bcol]     = b0;
        *(float4*)&Bs[brow + 8][bcol] = b1;
        __syncthreads();
#pragma unroll
        for (int kk = 0; kk < TBK; ++kk) {
            float4 x0 = *(const float4*)&As[kk][tr << 2];
            float4 x1 = *(const float4*)&As[kk][(tr << 2) + 64];
            float4 y0 = *(const float4*)&Bs[kk][tc << 2];
            float4 y1 = *(const float4*)&Bs[kk][(tc << 2) + 64];
            float xa[8] = {x0.x, x0.y, x0.z, x0.w, x1.x, x1.y, x1.z, x1.w};
            float yb[8] = {y0.x, y0.y, y0.z, y0.w, y1.x, y1.y, y1.z, y1.w};
#pragma unroll
            for (int i = 0; i < 8; ++i)
#pragma unroll
                for (int j = 0; j < 8; ++j)
                    acc[i][j] = fmaf(xa[i], yb[j], acc[i][j]);
        }
    }

#pragma unroll
    for (int ih = 0; ih < 2; ++ih) {
#pragma unroll
        for (int i = 0; i < 4; ++i) {
            int r = row0 + (tr << 2) + ih * 64 + i;
#pragma unroll
            for (int jh = 0; jh < 2; ++jh) {
                int c = col0 + (tc << 2) + jh * 64;
                size_t off = (size_t)r * ldc + c;
                float4 v = *(const float4*)&acc[ih * 4 + i][jh * 4];
                if (EPI == 1) {
                    float4 bb = *(const float4*)(aux + c);
                    float t0;
                    t0 = v.x + bb.x; v.x = fmaxf(t0, 0.f) + log1pf(expf(-fabsf(t0)));
                    t0 = v.y + bb.y; v.y = fmaxf(t0, 0.f) + log1pf(expf(-fabsf(t0)));
                    t0 = v.z + bb.z; v.z = fmaxf(t0, 0.f) + log1pf(expf(-fabsf(t0)));
                    t0 = v.w + bb.w; v.w = fmaxf(t0, 0.f) + log1pf(expf(-fabsf(t0)));
                } else if (EPI == 2) {
                    float4 rr = *(const float4*)(aux + off);
                    v.x += rr.x; v.y += rr.y; v.z += rr.z; v.w += rr.w;
                }
                *(float4*)(C + off) = v;
            }
        }
    }
}

// ---------------------------------------------------------------- xproj skinny GEMM, split-K
__global__ __launch_bounds__(256) void xproj_k(const float* __restrict__ A,
                                               const float* __restrict__ W,
                                               float* __restrict__ part)
{
    int row = blockIdx.x * 256 + threadIdx.x;
    int cg  = blockIdx.y;
    int ks  = blockIdx.z;
    const float4* a4 = (const float4*)(A + (size_t)row * D_INNER + ks * XKC);
    const float* w = W + (size_t)ks * XKC * 96 + cg * 8;
    float acc[8] = {};
#pragma unroll 2
    for (int k4 = 0; k4 < XKC / 4; ++k4) {
        float4 av = a4[k4];
        const float* wk = w + (size_t)k4 * 4 * 96;
        float a0 = av.x, a1 = av.y, a2 = av.z, a3 = av.w;
#pragma unroll
        for (int kk = 0; kk < 4; ++kk) {
            float ak = (kk == 0) ? a0 : (kk == 1) ? a1 : (kk == 2) ? a2 : a3;
            float4 w0 = *(const float4*)(wk + (size_t)kk * 96);
            float4 w1 = *(const float4*)(wk + (size_t)kk * 96 + 4);
            acc[0] = fmaf(ak, w0.x, acc[0]);
            acc[1] = fmaf(ak, w0.y, acc[1]);
            acc[2] = fmaf(ak, w0.z, acc[2]);
            acc[3] = fmaf(ak, w0.w, acc[3]);
            acc[4] = fmaf(ak, w1.x, acc[4]);
            acc[5] = fmaf(ak, w1.y, acc[5]);
            acc[6] = fmaf(ak, w1.z, acc[6]);
            acc[7] = fmaf(ak, w1.w, acc[7]);
        }
    }
    float* p = part + ((size_t)ks * NTOK + row) * 96 + cg * 8;
    *(float4*)p       = *(float4*)&acc[0];
    *(float4*)(p + 4) = *(float4*)&acc[4];
}

__global__ __launch_bounds__(256) void xreduce_k(const float* __restrict__ part,
                                                 float* __restrict__ dbc)
{
    int i = blockIdx.x * 256 + threadIdx.x;
    const float4* p = (const float4*)part;
    float4 s0 = p[i];
    float4 s1 = p[i + 98304];
    float4 s2 = p[i + 2 * 98304];
    float4 s3 = p[i + 3 * 98304];
    float4 s;
    s.x = (s0.x + s1.x) + (s2.x + s3.x);
    s.y = (s0.y + s1.y) + (s2.y + s3.y);
    s.z = (s0.z + s1.z) + (s2.z + s3.z);
    s.w = (s0.w + s1.w) + (s2.w + s3.w);
    ((float4*)dbc)[i] = s;
}

// ------------------------------------------------- depthwise causal conv + SiLU (4 l per thread)
__global__ __launch_bounds__(256) void conv_silu_kernel(const float* __restrict__ xz,
                                                        const float* __restrict__ conv_w,
                                                        const float* __restrict__ conv_b,
                                                        float* __restrict__ uc)
{
    int idx = blockIdx.x * 256 + threadIdx.x;     // over NTOK*D_INNER/4
    if (idx >= NTOK * D_INNER / 4) return;
    int d   = idx & (D_INNER - 1);
    int g4  = idx >> 11;                          // group of 4 rows
    int b   = g4 / (LSEQ / 4);
    int l0  = (g4 % (LSEQ / 4)) * 4;
    int bl0 = b * LSEQ + l0;
    float4 w = ((const float4*)conv_w)[d];
    float bb = conv_b[d];
    float t[7];                                   // rows l0-3 .. l0+3
#pragma unroll
    for (int k = 0; k < 7; ++k) {
        int l = l0 - 3 + k;
        t[k] = (l >= 0) ? xz[(size_t)(bl0 - 3 + k) * (2 * D_INNER) + d] : 0.f;
    }
#pragma unroll
    for (int j = 0; j < 4; ++j) {
        float acc = bb + w.x * t[j] + w.y * t[j+1] + w.z * t[j+2] + w.w * t[j+3];
        uc[(size_t)(bl0 + j) * D_INNER + d] = acc / (1.f + expf(-acc));
    }
}

// ---------------------------------------------------------------- chunked scan (thread-per-channel)
__global__ __launch_bounds__(256) void scan1_kernel(const float* __restrict__ delta,
                                                    const float* __restrict__ uc,
                                                    const float* __restrict__ dbc,
                                                    const float* __restrict__ A_log,
                                                    float* __restrict__ carry_A,
                                                    float* __restrict__ carry_h)
{
    __shared__ float Bs[SCL][16];
    int tid = threadIdx.x;
    int chunk = blockIdx.x, dg = blockIdx.y, b = blockIdx.z;
    int d = dg * 256 + tid;
    int rb0 = b * LSEQ + chunk * SCL;

    for (int i = tid; i < SCL * 16; i += 256) {
        int l = i >> 4, n = i & 15;
        Bs[l][n] = dbc[(size_t)(rb0 + l) * 96 + DT_RANK + n];
    }
    __syncthreads();

    float A2[16];
#pragma unroll
    for (int q = 0; q < 4; ++q) {
        float4 a = *(const float4*)&A_log[d * D_STATE + q * 4];
        A2[q*4+0] = -expf(a.x) * LOG2E;
        A2[q*4+1] = -expf(a.y) * LOG2E;
        A2[q*4+2] = -expf(a.z) * LOG2E;
        A2[q*4+3] = -expf(a.w) * LOG2E;
    }

    float h[16];
#pragma unroll
    for (int n = 0; n < 16; ++n) h[n] = 0.f;
    float sdv = 0.f;

    const float* dp = delta + (size_t)rb0 * D_INNER + d;
    const float* up = uc    + (size_t)rb0 * D_INNER + d;

    float dv = dp[0], uv = up[0];
    for (int l = 0; l < SCL; ++l) {
        float dvn = 0.f, uvn = 0.f;
        if (l + 1 < SCL) { dvn = dp[(l+1) * D_INNER]; uvn = up[(l+1) * D_INNER]; }
        float du = dv * uv;
        sdv += dv;
#pragma unroll
        for (int q = 0; q < 4; ++q) {
            float4 bq = *(const float4*)&Bs[l][q * 4];
            h[q*4+0] = fmaf(exp2f(dv * A2[q*4+0]), h[q*4+0], du * bq.x);
            h[q*4+1] = fmaf(exp2f(dv * A2[q*4+1]), h[q*4+1], du * bq.y);
            h[q*4+2] = fmaf(exp2f(dv * A2[q*4+2]), h[q*4+2], du * bq.z);
            h[q*4+3] = fmaf(exp2f(dv * A2[q*4+3]), h[q*4+3], du * bq.w);
        }
        dv = dvn; uv = uvn;
    }

    size_t cb = (((size_t)chunk * 2 + b) * D_INNER + d) * D_STATE;
#pragma unroll
    for (int q = 0; q < 4; ++q) {
        float4 ap, hh;
        ap.x = exp2f(sdv * A2[q*4+0]); ap.y = exp2f(sdv * A2[q*4+1]);
        ap.z = exp2f(sdv * A2[q*4+2]); ap.w = exp2f(sdv * A2[q*4+3]);
        hh.x = h[q*4+0]; hh.y = h[q*4+1]; hh.z = h[q*4+2]; hh.w = h[q*4+3];
        *(float4*)&carry_A[cb + q * 4] = ap;
        *(float4*)&carry_h[cb + q * 4] = hh;
    }
}

__global__ __launch_bounds__(256) void scan2_kernel(const float* __restrict__ carry_A,
                                                    float* __restrict__ carry_h)
{
    int idx = blockIdx.x * 256 + threadIdx.x;
    float h = 0.f;
#pragma unroll
    for (int c = 0; c < SCH; ++c) {
        size_t a = (size_t)c * (2 * D_INNER * D_STATE) + idx;
        float Ap = carry_A[a];
        float he = carry_h[a];
        carry_h[a] = h;
        h = fmaf(Ap, h, he);
    }
}

__global__ __launch_bounds__(256) void scan3_kernel(const float* __restrict__ delta,
                                                    const float* __restrict__ uc,
                                                    const float* __restrict__ dbc,
                                                    const float* __restrict__ xz,
                                                    const float* __restrict__ A_log,
                                                    const float* __restrict__ Dp,
                                                    const float* __restrict__ carry_h,
                                                    short* __restrict__ ygh,
                                                    short* __restrict__ ygl)
{
    __shared__ float Bs[SCL][16];
    __shared__ float Cs[SCL][16];
    int tid = threadIdx.x;
    int chunk = blockIdx.x, dg = blockIdx.y, b = blockIdx.z;
    int d = dg * 256 + tid;
    int rb0 = b * LSEQ + chunk * SCL;

    for (int i = tid; i < SCL * 32; i += 256) {
        int l = i >> 5, o = i & 31;
        float v = dbc[(size_t)(rb0 + l) * 96 + DT_RANK + o];
        if (o < 16) Bs[l][o] = v; else Cs[l][o - 16] = v;
    }
    __syncthreads();

    float A2[16];
#pragma unroll
    for (int q = 0; q < 4; ++q) {
        float4 a = *(const float4*)&A_log[d * D_STATE + q * 4];
        A2[q*4+0] = -expf(a.x) * LOG2E;
        A2[q*4+1] = -expf(a.y) * LOG2E;
        A2[q*4+2] = -expf(a.z) * LOG2E;
        A2[q*4+3] = -expf(a.w) * LOG2E;
    }
    float Dv = Dp[d];

    float h[16];
    size_t cb = (((size_t)chunk * 2 + b) * D_INNER + d) * D_STATE;
#pragma unroll
    for (int q = 0; q < 4; ++q) {
        float4 hh = *(const float4*)&carry_h[cb + q * 4];
        h[q*4+0] = hh.x; h[q*4+1] = hh.y; h[q*4+2] = hh.z; h[q*4+3] = hh.w;
    }

    const float* dp = delta + (size_t)rb0 * D_INNER + d;
    const float* up = uc    + (size_t)rb0 * D_INNER + d;
    const float* zp = xz    + (size_t)rb0 * (2 * D_INNER) + D_INNER + d;
    short* yhp = ygh + (size_t)rb0 * D_INNER + d;
    short* ylp = ygl + (size_t)rb0 * D_INNER + d;

    float dv = dp[0], uv = up[0], zv = zp[0];
    for (int l = 0; l < SCL; ++l) {
        float dvn = 0.f, uvn = 0.f, zvn = 0.f;
        if (l + 1 < SCL) {
            dvn = dp[(l+1) * D_INNER];
            uvn = up[(l+1) * D_INNER];
            zvn = zp[(size_t)(l+1) * (2 * D_INNER)];
        }
        float du = dv * uv;
        float y = 0.f;
#pragma unroll
        for (int q = 0; q < 4; ++q) {
            float4 bq = *(const float4*)&Bs[l][q * 4];
            float4 cq = *(const float4*)&Cs[l][q * 4];
            h[q*4+0] = fmaf(exp2f(dv * A2[q*4+0]), h[q*4+0], du * bq.x);
            h[q*4+1] = fmaf(exp2f(dv * A2[q*4+1]), h[q*4+1], du * bq.y);
            h[q*4+2] = fmaf(exp2f(dv * A2[q*4+2]), h[q*4+2], du * bq.z);
            h[q*4+3] = fmaf(exp2f(dv * A2[q*4+3]), h[q*4+3], du * bq.w);
            y = fmaf(h[q*4+0], cq.x, y);
            y = fmaf(h[q*4+1], cq.y, y);
            y = fmaf(h[q*4+2], cq.z, y);
            y = fmaf(h[q*4+3], cq.w, y);
        }
        float yd  = fmaf(uv, Dv, y);
        float val = yd * (zv / (1.f + expf(-zv)));
        short hh, ll;
        split_hi_lo(val, hh, ll);
        yhp[l * D_INNER] = hh;
        ylp[l * D_INNER] = ll;
        dv = dvn; uv = uvn; zv = zvn;
    }
}

// ---------------------------------------------------------------- serial scan (ws fallback)
__global__ __launch_bounds__(256) void scan_kernel(const float* __restrict__ delta,
                                                   const float* __restrict__ uc,
                                                   const float* __restrict__ dbc,
                                                   const float* __restrict__ xz,
                                                   const float* __restrict__ A_log,
                                                   const float* __restrict__ Dp,
                                                   short* __restrict__ ygh,
                                                   short* __restrict__ ygl)
{
    int tid = threadIdx.x;
    int g = tid >> 4, n = tid & 15;
    int bid = blockIdx.x;
    int b = bid >> 7;
    int d = (bid & 127) * 16 + g;
    float Adn = -expf(A_log[d * D_STATE + n]);
    float Dv  = Dp[d];
    float h = 0.f;
    size_t rowb = (size_t)b * LSEQ;

    float dv = delta[rowb * D_INNER + d];
    float uv = uc[rowb * D_INNER + d];
    float Bv = dbc[rowb * 96 + DT_RANK + n];
    float Cv = dbc[rowb * 96 + DT_RANK + D_STATE + n];

    for (int l = 0; l < LSEQ; ++l) {
        float dv_n = 0.f, uv_n = 0.f, Bv_n = 0.f, Cv_n = 0.f;
        if (l + 1 < LSEQ) {
            size_t r = rowb + l + 1;
            dv_n = delta[r * D_INNER + d];
            uv_n = uc[r * D_INNER + d];
            Bv_n = dbc[r * 96 + DT_RANK + n];
            Cv_n = dbc[r * 96 + DT_RANK + D_STATE + n];
        }
        float dA = expf(dv * Adn);
        h = fmaf(dA, h, dv * uv * Bv);
        float p = h * Cv;
        p += __shfl_xor(p, 1);
        p += __shfl_xor(p, 2);
        p += __shfl_xor(p, 4);
        p += __shfl_xor(p, 8);
        if (n == 0) {
            size_t r = rowb + l;
            float zv = xz[r * (2 * D_INNER) + D_INNER + d];
            float y  = fmaf(uv, Dv, p);
            float val = y * (zv / (1.f + expf(-zv)));
            short hh, ll;
            split_hi_lo(val, hh, ll);
            ygh[r * D_INNER + d] = hh;
            ygl[r * D_INNER + d] = ll;
        }
        dv = dv_n; uv = uv_n; Bv = Bv_n; Cv = Cv_n;
    }
}

// ---------------------------------------------------------------- launch
extern "C" void kernel_launch(void* const* d_in, const int* in_sizes, int n_in,
                              void* d_out, int out_size, void* d_ws, size_t ws_size,
                              hipStream_t stream)
{
    const float* x      = (const float*)d_in[0];
    const float* ln_w   = (const float*)d_in[1];
    const float* ln_b   = (const float*)d_in[2];
    const float* W_in   = (const float*)d_in[3];
    const float* conv_w = (const float*)d_in[4];
    const float* conv_b = (const float*)d_in[5];
    const float* W_xprj = (const float*)d_in[6];
    const float* W_dt   = (const float*)d_in[7];
    const float* b_dt   = (const float*)d_in[8];
    const float* A_log  = (const float*)d_in[9];
    const float* Dp     = (const float*)d_in[10];
    const float* W_out  = (const float*)d_in[11];
    float* out = (float*)d_out;

    // fp32 segments: 135,790,592 B
    float* xz    = (float*)d_ws;                          // 4096*4096
    float* uc    = xz    + (size_t)NTOK * 2 * D_INNER;    // 4096*2048
    float* dbc   = uc    + (size_t)NTOK * D_INNER;        // 4096*96
    float* delta = dbc   + (size_t)NTOK * 96;             // 4096*2048 (dead after scan3 -> reused as GEMM-out partials)
    // bf16 (short) region: 20 Mi shorts, phase-reused
    short* s0    = (short*)(delta + (size_t)NTOK * D_INNER);
    short* nh    = s0;                                    // phase A
    short* nl    = nh   + (size_t)NTOK * D_MODEL;
    short* wiTh  = nl   + (size_t)NTOK * D_MODEL;
    short* wiTl  = wiTh + (size_t)(2 * D_INNER) * D_MODEL;
    short* ygh   = s0;                                    // phase B (aliases A)
    short* ygl   = ygh  + (size_t)NTOK * D_INNER;
    short* woTh  = ygl  + (size_t)NTOK * D_INNER;
    short* woTl  = woTh + (size_t)D_MODEL * D_INNER;
    // xproj partials: alias dead phase-A region
    float* xpart = (float*)s0;
    // GEMM-out split-K partials: alias dead delta region (2 x 4096 x 1024 fp32 = 32MB)
    float* gpart = delta;
    // scan carries: 2 x 8 MiB after the bf16 region
    float* carry_A = (float*)(s0 + (size_t)20971520);
    float* carry_h = carry_A + (size_t)2 * D_INNER * D_STATE * SCH;

    size_t needed_base = (size_t)135790592 + (size_t)41943040;
    size_t needed_fast = needed_base + (size_t)2 * 2 * D_INNER * D_STATE * SCH * 4;
    if (ws_size < needed_base) return;
    bool fast_scan = (ws_size >= needed_fast);

    // 0. weight transpose+split
    cvtT_k<<<dim3(2 * D_INNER / 64, D_MODEL / 64), 256, 0, stream>>>(W_in, wiTh, wiTl, D_MODEL, 2 * D_INNER);
    cvtT_k<<<dim3(D_MODEL / 64, D_INNER / 64), 256, 0, stream>>>(W_out, woTh, woTl, D_INNER, D_MODEL);
    // 1. LayerNorm -> bf16 hi/lo
    ln_kernel<<<NTOK, 256, 0, stream>>>(x, ln_w, ln_b, nh, nl);
    // 2. xz = normed @ W_in   (bf16x3 MFMA, 2-phase prefetch + setprio)
    mgemm_k<0><<<dim3(2 * D_INNER / 128, NTOK / 128, 1), 256, 0, stream>>>(
        nh, nl, wiTh, wiTl, xz, 2 * D_INNER, D_MODEL, D_MODEL, nullptr);
    // 3. depthwise conv + SiLU (4 rows/thread sliding window)
    conv_silu_kernel<<<(NTOK * D_INNER / 4) / 256, 256, 0, stream>>>(xz, conv_w, conv_b, uc);
    // 4. dbc = uc @ W_xproj   (split-K skinny GEMM)
    xproj_k<<<dim3(NTOK / 256, 12, XKS), 256, 0, stream>>>(uc, W_xprj, xpart);
    xreduce_k<<<(NTOK * 96 / 4) / 256, 256, 0, stream>>>(xpart, dbc);
    // 5. delta = softplus(dt @ W_dt + b_dt)
    sgemm128_k<1><<<dim3(D_INNER / TBN, NTOK / TBM), 256, 0, stream>>>(
        dbc, 96, W_dt, D_INNER, delta, D_INNER, DT_RANK, b_dt);
    // 6. selective scan + gating -> bf16 hi/lo
    if (fast_scan) {
        scan1_kernel<<<dim3(SCH, D_INNER / 256, 2), 256, 0, stream>>>(
            delta, uc, dbc, A_log, carry_A, carry_h);
        scan2_kernel<<<(2 * D_INNER * D_STATE) / 256, 256, 0, stream>>>(carry_A, carry_h);
        scan3_kernel<<<dim3(SCH, D_INNER / 256, 2), 256, 0, stream>>>(
            delta, uc, dbc, xz, A_log, Dp, carry_h, ygh, ygl);
    } else {
        scan_kernel<<<256, 256, 0, stream>>>(delta, uc, dbc, xz, A_log, Dp, ygh, ygl);
    }
    // 7. GEMM-out split-K=2: partials into dead delta region (512 blocks = 2/CU)
    mgemm_k<0><<<dim3(D_MODEL / 128, NTOK / 128, 2), 256, 0, stream>>>(
        ygh, ygl, woTh, woTl, gpart, D_MODEL, D_INNER / 2, D_INNER, nullptr);
    // 8. out = x + p0 + p1
    outred_k<<<(NTOK * D_MODEL / 4) / 256, 256, 0, stream>>>(x, gpart, out);
}